// Round 10
// baseline (575.969 us; speedup 1.0000x reference)
//
#include <hip/hip_runtime.h>
#include <float.h>
#include <math.h>
#include <stdint.h>

#define M_ROWS 32768
#define K_CODES 8192
#define DDIM 256
#define BM 64
#define BN 128
#define NTILES (K_CODES / BN)   // 64
#define DELTA 0.009f
#define CAP 16

typedef __attribute__((ext_vector_type(8))) short short8;
typedef __attribute__((ext_vector_type(4))) float f32x4;

__device__ inline unsigned short f2bf(float f) {
    unsigned u = __float_as_uint(f);
    return (unsigned short)((u + 0x7fffu + ((u >> 16) & 1u)) >> 16);
}
__device__ inline unsigned fkey(float f) {
    unsigned u = __float_as_uint(f);
    return u ^ ((unsigned)((int)u >> 31) | 0x80000000u);
}
__device__ inline float fkey_inv(unsigned k) {
    unsigned u = (k & 0x80000000u) ? (k ^ 0x80000000u) : ~k;
    return __uint_as_float(u);
}

// ---------------- kernel 1: normalize E -> En (fp32) + En_b (bf16) ----------------
__global__ __launch_bounds__(256) void k_norm_E(const float* __restrict__ E,
                                                float* __restrict__ En,
                                                unsigned short* __restrict__ En_b) {
    int wid  = threadIdx.x >> 6;
    int lane = threadIdx.x & 63;
    int row  = blockIdx.x * 4 + wid;
    const float* e = E + (size_t)row * DDIM;
    float v[4];
    float ssq = 0.f;
#pragma unroll
    for (int p = 0; p < 4; ++p) { v[p] = e[lane + 64 * p]; ssq += v[p] * v[p]; }
#pragma unroll
    for (int off = 32; off >= 1; off >>= 1) ssq += __shfl_xor(ssq, off);
    float inv = 1.f / fmaxf(sqrtf(ssq), 1e-8f);
    float* o = En + (size_t)row * DDIM;
    unsigned short* ob = En_b + (size_t)row * DDIM;
#pragma unroll
    for (int p = 0; p < 4; ++p) {
        float nv = v[p] * inv;
        o[lane + 64 * p]  = nv;
        ob[lane + 64 * p] = f2bf(nv);
    }
}

// ---------------- kernel 2: two-pass MFMA filter, B direct global->VGPR ----------
// 512 thr = 8 waves. Each wave owns 16 codes (wc=wid) of the BN=128 tile and
// ALL BM=64 rows (af[4][8] = 128 VGPRs). B-fragments are loaded straight from
// global into a register double buffer (bA/bB, 64 VGPRs) -- no LDS in the loop.
// __launch_bounds__(512, 1): 256-VGPR budget, ~240 used, ZERO spill (R9 at
// (512,2) capped 128 VGPRs and spilled the B buffers -> 68 MB scratch writes).
// Pass A: register fmax -> exact row max. Pass B: recompute, emit >= max-DELTA.
__global__ __launch_bounds__(512, 1) void k_cand(
    const float* __restrict__ z,
    const unsigned short* __restrict__ En_b,
    unsigned char* __restrict__ cand_cnt,
    int* __restrict__ cand_k) {

    __shared__ unsigned rowmaxKey[BM];
    __shared__ int cnt[BM];
    __shared__ int list[BM][CAP];

    const int tid  = threadIdx.x;
    const int lane = tid & 63;
    const int wid  = tid >> 6;      // col-group 0..7
    const int lo   = lane & 15;
    const int hi   = lane >> 4;
    const int m0   = blockIdx.x * BM;

    if (tid < BM) { cnt[tid] = 0; rowmaxKey[tid] = 0u; }
    __syncthreads();

    // per-lane B base: code row = wid*16+lo, 16B sub-column hi within each 64B
    const char* bbase = (const char*)En_b + (size_t)(wid * 16 + lo) * 512 + hi * 16;

#define LOADT(buf, t)                                                           \
    {                                                                           \
        const char* bp_ = bbase + (size_t)(t) * (BN * 512);                     \
        _Pragma("unroll")                                                       \
        for (int ks_ = 0; ks_ < 8; ++ks_)                                       \
            buf[ks_] = *(const short8*)(bp_ + ks_ * 64);                        \
    }

    // issue first tile load early (covers af-setup latency)
    short8 bA[8], bB[8];
    LOADT(bA, 0);

    // ---- A fragments: load z fp32, normalize in-register, cvt bf16 ----
    // af[mi][ks]: row = mi*16 + lo (same rows for all 8 waves)
    short8 af[4][8];
#pragma unroll
    for (int mi = 0; mi < 4; ++mi) {
        const float* zr = z + (size_t)(m0 + mi * 16 + lo) * DDIM;
        float4 v[16];
        float ssq = 0.f;
#pragma unroll
        for (int ks = 0; ks < 8; ++ks) {
            int e0 = (ks * 4 + hi) * 8;
            v[2 * ks]     = *(const float4*)&zr[e0];
            v[2 * ks + 1] = *(const float4*)&zr[e0 + 4];
            float4 a = v[2 * ks], b = v[2 * ks + 1];
            ssq += a.x * a.x + a.y * a.y + a.z * a.z + a.w * a.w;
            ssq += b.x * b.x + b.y * b.y + b.z * b.z + b.w * b.w;
        }
        // 4 hi-lanes hold disjoint 64-element subsets of the row
        ssq += __shfl_xor(ssq, 16);
        ssq += __shfl_xor(ssq, 32);
        float inv = 1.f / fmaxf(sqrtf(ssq), 1e-8f);
#pragma unroll
        for (int ks = 0; ks < 8; ++ks) {
            float4 a = v[2 * ks], b = v[2 * ks + 1];
            short8 s8;
            s8[0] = (short)f2bf(a.x * inv); s8[1] = (short)f2bf(a.y * inv);
            s8[2] = (short)f2bf(a.z * inv); s8[3] = (short)f2bf(a.w * inv);
            s8[4] = (short)f2bf(b.x * inv); s8[5] = (short)f2bf(b.y * inv);
            s8[6] = (short)f2bf(b.z * inv); s8[7] = (short)f2bf(b.w * inv);
            af[mi][ks] = s8;
        }
    }

#define MFMA_TILE(buf, acc)                                                     \
    _Pragma("unroll")                                                           \
    for (int ks_ = 0; ks_ < 8; ++ks_) {                                         \
        _Pragma("unroll")                                                       \
        for (int mi_ = 0; mi_ < 4; ++mi_)                                       \
            acc[mi_] = __builtin_amdgcn_mfma_f32_16x16x32_bf16(                 \
                af[mi_][ks_], buf[ks_], acc[mi_], 0, 0, 0);                     \
    }

    // ================= PASS A: exact row max =================
    float pmax[16];
#pragma unroll
    for (int s = 0; s < 16; ++s) pmax[s] = -FLT_MAX;

#define COMPA(buf)                                                              \
    {                                                                           \
        f32x4 acc[4];                                                           \
        _Pragma("unroll") for (int mi_ = 0; mi_ < 4; ++mi_)                     \
            acc[mi_] = (f32x4){0.f, 0.f, 0.f, 0.f};                             \
        MFMA_TILE(buf, acc)                                                     \
        _Pragma("unroll") for (int mi_ = 0; mi_ < 4; ++mi_)                     \
            _Pragma("unroll") for (int r_ = 0; r_ < 4; ++r_)                    \
                pmax[mi_ * 4 + r_] = fmaxf(pmax[mi_ * 4 + r_], acc[mi_][r_]);   \
    }

    for (int t = 0; t < NTILES; t += 2) {
        LOADT(bB, t + 1);
        COMPA(bA);
        if (t + 2 < NTILES) LOADT(bA, t + 2);
        COMPA(bB);
    }

    // reduce row max across the 16 lo-lanes, publish via LDS atomicMax
#pragma unroll
    for (int s = 0; s < 16; ++s) {
        float w = pmax[s];
        w = fmaxf(w, __shfl_xor(w, 1));
        w = fmaxf(w, __shfl_xor(w, 2));
        w = fmaxf(w, __shfl_xor(w, 4));
        w = fmaxf(w, __shfl_xor(w, 8));
        if (lo == 0) {
            int row = (s >> 2) * 16 + hi * 4 + (s & 3);
            atomicMax(&rowmaxKey[row], fkey(w));
        }
    }
    __syncthreads();   // all waves' maxima published

    float thr[16];
#pragma unroll
    for (int s = 0; s < 16; ++s) {
        int row = (s >> 2) * 16 + hi * 4 + (s & 3);
        thr[s] = fkey_inv(rowmaxKey[row]) - DELTA;
    }

    // ================= PASS B: emit candidates =================
#define COMPB(buf, t)                                                           \
    {                                                                           \
        f32x4 acc[4];                                                           \
        _Pragma("unroll") for (int mi_ = 0; mi_ < 4; ++mi_)                     \
            acc[mi_] = (f32x4){0.f, 0.f, 0.f, 0.f};                             \
        MFMA_TILE(buf, acc)                                                     \
        const int kv_ = (t) * BN + wid * 16 + lo;                               \
        _Pragma("unroll") for (int mi_ = 0; mi_ < 4; ++mi_)                     \
            _Pragma("unroll") for (int r_ = 0; r_ < 4; ++r_) {                  \
                if (acc[mi_][r_] >= thr[mi_ * 4 + r_]) {                        \
                    int row_ = mi_ * 16 + hi * 4 + r_;                          \
                    int pos_ = atomicAdd(&cnt[row_], 1);                        \
                    if (pos_ < CAP) list[row_][pos_] = kv_;                     \
                }                                                               \
            }                                                                   \
    }

    LOADT(bA, 0);
    for (int t = 0; t < NTILES; t += 2) {
        LOADT(bB, t + 1);
        COMPB(bA, t);
        if (t + 2 < NTILES) LOADT(bA, t + 2);
        COMPB(bB, t + 1);
    }
    __syncthreads();   // lists complete

    if (tid < BM) {
        int c = cnt[tid];
        cand_cnt[m0 + tid] = (unsigned char)(c > CAP ? 255 : c);
        int n = c < CAP ? c : CAP;
        for (int j = 0; j < n; ++j) cand_k[(size_t)(m0 + tid) * CAP + j] = list[tid][j];
    }
#undef LOADT
#undef MFMA_TILE
#undef COMPA
#undef COMPB
}

// ---------------- kernel 3: rescore + gather / zq_st / per-row loss / idx ----------------
__global__ __launch_bounds__(256) void k_final(const float* __restrict__ z,
                                               const float* __restrict__ E,
                                               const float* __restrict__ En,
                                               const unsigned char* __restrict__ cand_cnt,
                                               const int* __restrict__ cand_k,
                                               float* __restrict__ out,
                                               float* __restrict__ rowloss) {
    __shared__ float zl[4][256];
    int wid  = threadIdx.x >> 6;
    int lane = threadIdx.x & 63;
    int m    = blockIdx.x * 4 + wid;

    const float* zr = z + (size_t)m * DDIM;
    const float4 zz = *(const float4*)&zr[lane * 4];

    int   c  = cand_cnt[m];
    float bv = -FLT_MAX;
    int   bk = 0x7fffffff;
    if (c != 255) {
        for (int j = 0; j < c; ++j) {
            int k = cand_k[(size_t)m * CAP + j];
            const float4 ee = *(const float4*)&En[(size_t)k * DDIM + lane * 4];
            float s = zz.x * ee.x + zz.y * ee.y + zz.z * ee.z + zz.w * ee.w;
#pragma unroll
            for (int off = 1; off < 64; off <<= 1) s += __shfl_xor(s, off);
            if (s > bv || (s == bv && k < bk)) { bv = s; bk = k; }
        }
    } else {
        // insurance fallback: wave-parallel full fp32 scan, z staged in LDS
        *(float4*)&zl[wid][lane * 4] = zz;
        asm volatile("s_waitcnt lgkmcnt(0)" ::: "memory");
        for (int kb = 0; kb < K_CODES; kb += 64) {
            int k = kb + lane;
            const float4* er = (const float4*)&En[(size_t)k * DDIM];
            float s0 = 0.f, s1 = 0.f, s2 = 0.f, s3 = 0.f;
#pragma unroll 8
            for (int d4 = 0; d4 < 64; ++d4) {
                float4 e  = er[d4];
                float4 zd = *(const float4*)&zl[wid][d4 * 4];
                s0 += zd.x * e.x; s1 += zd.y * e.y;
                s2 += zd.z * e.z; s3 += zd.w * e.w;
            }
            float s = (s0 + s1) + (s2 + s3);
            if (s > bv || (s == bv && k < bk)) { bv = s; bk = k; }
        }
#pragma unroll
        for (int off = 1; off < 64; off <<= 1) {
            float ov = __shfl_xor(bv, off);
            int   ok = __shfl_xor(bk, off);
            if (ov > bv || (ov == bv && ok < bk)) { bv = ov; bk = ok; }
        }
    }
    const int idx = bk;

    const float* er = E + (size_t)idx * DDIM;
    float zv[4], ev[4];
    float sz = 0.f, se = 0.f;
#pragma unroll
    for (int p = 0; p < 4; ++p) {
        zv[p] = zr[lane + 64 * p]; sz += zv[p] * zv[p];
        ev[p] = er[lane + 64 * p]; se += ev[p] * ev[p];
    }
#pragma unroll
    for (int off = 32; off >= 1; off >>= 1) {
        sz += __shfl_xor(sz, off);
        se += __shfl_xor(se, off);
    }
    float nz = fmaxf(sqrtf(sz), 1e-8f);
    float ne = fmaxf(sqrtf(se), 1e-8f);

    float rs = 0.f;
    float* zq = out + 1 + (size_t)m * DDIM;
#pragma unroll
    for (int p = 0; p < 4; ++p) {
        float zn = zv[p] / nz;
        float en = ev[p] / ne;
        float d  = en - zn;
        rs += d * d;
        zq[lane + 64 * p] = zv[p] + (ev[p] - zv[p]);
    }
#pragma unroll
    for (int off = 32; off >= 1; off >>= 1) rs += __shfl_xor(rs, off);

    if (lane == 0) {
        rowloss[m] = rs;
        out[1 + (size_t)M_ROWS * DDIM + m] = (float)idx;
    }
}

// ---------------- kernel 4: deterministic loss reduction ----------------
__global__ __launch_bounds__(256) void k_loss(const float* __restrict__ rowloss,
                                              float* __restrict__ out) {
    __shared__ double sm[256];
    double s = 0.0;
    for (int i = threadIdx.x; i < M_ROWS; i += 256) s += (double)rowloss[i];
    sm[threadIdx.x] = s;
    __syncthreads();
    for (int st = 128; st > 0; st >>= 1) {
        if (threadIdx.x < st) sm[threadIdx.x] += sm[threadIdx.x + st];
        __syncthreads();
    }
    if (threadIdx.x == 0) {
        float c = (float)(sm[0] / (double)((size_t)M_ROWS * DDIM));
        out[0] = c + 0.05f * c;
    }
}

extern "C" void kernel_launch(void* const* d_in, const int* in_sizes, int n_in,
                              void* d_out, int out_size, void* d_ws, size_t ws_size,
                              hipStream_t stream) {
    const float* z = (const float*)d_in[0];
    const float* E = (const float*)d_in[1];
    float* out = (float*)d_out;

    char* ws = (char*)d_ws;
    size_t off = 0;
    float*          En       = (float*)(ws + off);          off += (size_t)K_CODES * DDIM * 4;  // 8 MB
    unsigned short* En_b     = (unsigned short*)(ws + off); off += (size_t)K_CODES * DDIM * 2;  // 4 MB
    int*            cand_k   = (int*)(ws + off);            off += (size_t)M_ROWS * CAP * 4;    // 2 MB
    unsigned char*  cand_cnt = (unsigned char*)(ws + off);  off += (size_t)M_ROWS;              // 32 KB
    float*          rowloss  = (float*)(ws + off);

    k_norm_E<<<K_CODES / 4, 256, 0, stream>>>(E, En, En_b);
    k_cand<<<M_ROWS / BM, 512, 0, stream>>>(z, En_b, cand_cnt, cand_k);
    k_final<<<M_ROWS / 4, 256, 0, stream>>>(z, E, En, cand_cnt, cand_k, out, rowloss);
    k_loss<<<1, 256, 0, stream>>>(rowloss, out);
}

// Round 11
// 544.048 us; speedup vs baseline: 1.0587x; 1.0587x over previous
//
#include <hip/hip_runtime.h>
#include <float.h>
#include <math.h>
#include <stdint.h>

#define M_ROWS 32768
#define K_CODES 8192
#define DDIM 256
#define BM 64
#define BN 64
#define NTILES (K_CODES / BN)   // 128
#define DELTA 0.009f
#define CAP 16

typedef __attribute__((ext_vector_type(8))) short short8;
typedef __attribute__((ext_vector_type(4))) float f32x4;

__device__ inline unsigned short f2bf(float f) {
    unsigned u = __float_as_uint(f);
    return (unsigned short)((u + 0x7fffu + ((u >> 16) & 1u)) >> 16);
}
__device__ inline unsigned fkey(float f) {
    unsigned u = __float_as_uint(f);
    return u ^ ((unsigned)((int)u >> 31) | 0x80000000u);
}
__device__ inline float fkey_inv(unsigned k) {
    unsigned u = (k & 0x80000000u) ? (k ^ 0x80000000u) : ~k;
    return __uint_as_float(u);
}

// ---------------- kernel 1: normalize E -> En (fp32) + En_b (bf16) ----------------
__global__ __launch_bounds__(256) void k_norm_E(const float* __restrict__ E,
                                                float* __restrict__ En,
                                                unsigned short* __restrict__ En_b) {
    int wid  = threadIdx.x >> 6;
    int lane = threadIdx.x & 63;
    int row  = blockIdx.x * 4 + wid;
    const float* e = E + (size_t)row * DDIM;
    float v[4];
    float ssq = 0.f;
#pragma unroll
    for (int p = 0; p < 4; ++p) { v[p] = e[lane + 64 * p]; ssq += v[p] * v[p]; }
#pragma unroll
    for (int off = 32; off >= 1; off >>= 1) ssq += __shfl_xor(ssq, off);
    float inv = 1.f / fmaxf(sqrtf(ssq), 1e-8f);
    float* o = En + (size_t)row * DDIM;
    unsigned short* ob = En_b + (size_t)row * DDIM;
#pragma unroll
    for (int p = 0; p < 4; ++p) {
        float nv = v[p] * inv;
        o[lane + 64 * p]  = nv;
        ob[lane + 64 * p] = f2bf(nv);
    }
}

// ---------------- kernel 2: two-pass MFMA filter, B direct global->VGPR ----------
// 256 thr = 4 waves (KEY CHANGE: 512-thread blocks cap the allocator at 128
// VGPR on gfx950 -- observed R7-R10 -- and this kernel needs ~250; 256-thread
// blocks with __launch_bounds__(256,2) get a 256-VGPR budget -> no spill).
// Each wave owns 16 codes (wc=wid) of the BN=64 tile and ALL BM=64 rows
// (af[4][8] = 128 VGPRs). B-fragments load straight from global into a
// register double buffer (bA/bB, 64 VGPRs) -- no LDS in the hot loop.
// ~250 VGPR -> 2 blocks/CU co-resident, independently de-phased (R8 mechanism).
// Pass A: register fmax -> exact row max. Pass B: recompute, emit >= max-DELTA.
__global__ __launch_bounds__(256, 2) void k_cand(
    const float* __restrict__ z,
    const unsigned short* __restrict__ En_b,
    unsigned char* __restrict__ cand_cnt,
    int* __restrict__ cand_k) {

    __shared__ unsigned rowmaxKey[BM];
    __shared__ int cnt[BM];
    __shared__ int list[BM][CAP];

    const int tid  = threadIdx.x;
    const int lane = tid & 63;
    const int wid  = tid >> 6;      // col-group 0..3
    const int lo   = lane & 15;
    const int hi   = lane >> 4;
    const int m0   = blockIdx.x * BM;

    if (tid < BM) { cnt[tid] = 0; rowmaxKey[tid] = 0u; }
    __syncthreads();

    // per-lane B base: code row = wid*16+lo, 16B sub-column hi within each 64B
    const char* bbase = (const char*)En_b + (size_t)(wid * 16 + lo) * 512 + hi * 16;

#define LOADT(buf, t)                                                           \
    {                                                                           \
        const char* bp_ = bbase + (size_t)(t) * (BN * 512);                     \
        _Pragma("unroll")                                                       \
        for (int ks_ = 0; ks_ < 8; ++ks_)                                       \
            buf[ks_] = *(const short8*)(bp_ + ks_ * 64);                        \
    }

    // issue first tile load early (covers af-setup latency)
    short8 bA[8], bB[8];
    LOADT(bA, 0);

    // ---- A fragments: load z fp32, normalize in-register, cvt bf16 ----
    // af[mi][ks]: row = mi*16 + lo (same rows for all 4 waves)
    short8 af[4][8];
#pragma unroll
    for (int mi = 0; mi < 4; ++mi) {
        const float* zr = z + (size_t)(m0 + mi * 16 + lo) * DDIM;
        float4 v[16];
        float ssq = 0.f;
#pragma unroll
        for (int ks = 0; ks < 8; ++ks) {
            int e0 = (ks * 4 + hi) * 8;
            v[2 * ks]     = *(const float4*)&zr[e0];
            v[2 * ks + 1] = *(const float4*)&zr[e0 + 4];
            float4 a = v[2 * ks], b = v[2 * ks + 1];
            ssq += a.x * a.x + a.y * a.y + a.z * a.z + a.w * a.w;
            ssq += b.x * b.x + b.y * b.y + b.z * b.z + b.w * b.w;
        }
        // 4 hi-lanes hold disjoint 64-element subsets of the row
        ssq += __shfl_xor(ssq, 16);
        ssq += __shfl_xor(ssq, 32);
        float inv = 1.f / fmaxf(sqrtf(ssq), 1e-8f);
#pragma unroll
        for (int ks = 0; ks < 8; ++ks) {
            float4 a = v[2 * ks], b = v[2 * ks + 1];
            short8 s8;
            s8[0] = (short)f2bf(a.x * inv); s8[1] = (short)f2bf(a.y * inv);
            s8[2] = (short)f2bf(a.z * inv); s8[3] = (short)f2bf(a.w * inv);
            s8[4] = (short)f2bf(b.x * inv); s8[5] = (short)f2bf(b.y * inv);
            s8[6] = (short)f2bf(b.z * inv); s8[7] = (short)f2bf(b.w * inv);
            af[mi][ks] = s8;
        }
    }

#define MFMA_TILE(buf, acc)                                                     \
    _Pragma("unroll")                                                           \
    for (int ks_ = 0; ks_ < 8; ++ks_) {                                         \
        _Pragma("unroll")                                                       \
        for (int mi_ = 0; mi_ < 4; ++mi_)                                       \
            acc[mi_] = __builtin_amdgcn_mfma_f32_16x16x32_bf16(                 \
                af[mi_][ks_], buf[ks_], acc[mi_], 0, 0, 0);                     \
    }

    // ================= PASS A: exact row max =================
    float pmax[16];
#pragma unroll
    for (int s = 0; s < 16; ++s) pmax[s] = -FLT_MAX;

#define COMPA(buf)                                                              \
    {                                                                           \
        f32x4 acc[4];                                                           \
        _Pragma("unroll") for (int mi_ = 0; mi_ < 4; ++mi_)                     \
            acc[mi_] = (f32x4){0.f, 0.f, 0.f, 0.f};                             \
        MFMA_TILE(buf, acc)                                                     \
        _Pragma("unroll") for (int mi_ = 0; mi_ < 4; ++mi_)                     \
            _Pragma("unroll") for (int r_ = 0; r_ < 4; ++r_)                    \
                pmax[mi_ * 4 + r_] = fmaxf(pmax[mi_ * 4 + r_], acc[mi_][r_]);   \
    }

    for (int t = 0; t < NTILES; t += 2) {
        LOADT(bB, t + 1);
        COMPA(bA);
        if (t + 2 < NTILES) LOADT(bA, t + 2);
        COMPA(bB);
    }

    // reduce row max across the 16 lo-lanes, publish via LDS atomicMax
#pragma unroll
    for (int s = 0; s < 16; ++s) {
        float w = pmax[s];
        w = fmaxf(w, __shfl_xor(w, 1));
        w = fmaxf(w, __shfl_xor(w, 2));
        w = fmaxf(w, __shfl_xor(w, 4));
        w = fmaxf(w, __shfl_xor(w, 8));
        if (lo == 0) {
            int row = (s >> 2) * 16 + hi * 4 + (s & 3);
            atomicMax(&rowmaxKey[row], fkey(w));
        }
    }
    __syncthreads();   // all waves' maxima published

    float thr[16];
#pragma unroll
    for (int s = 0; s < 16; ++s) {
        int row = (s >> 2) * 16 + hi * 4 + (s & 3);
        thr[s] = fkey_inv(rowmaxKey[row]) - DELTA;
    }

    // ================= PASS B: emit candidates =================
#define COMPB(buf, t)                                                           \
    {                                                                           \
        f32x4 acc[4];                                                           \
        _Pragma("unroll") for (int mi_ = 0; mi_ < 4; ++mi_)                     \
            acc[mi_] = (f32x4){0.f, 0.f, 0.f, 0.f};                             \
        MFMA_TILE(buf, acc)                                                     \
        const int kv_ = (t) * BN + wid * 16 + lo;                               \
        _Pragma("unroll") for (int mi_ = 0; mi_ < 4; ++mi_)                     \
            _Pragma("unroll") for (int r_ = 0; r_ < 4; ++r_) {                  \
                if (acc[mi_][r_] >= thr[mi_ * 4 + r_]) {                        \
                    int row_ = mi_ * 16 + hi * 4 + r_;                          \
                    int pos_ = atomicAdd(&cnt[row_], 1);                        \
                    if (pos_ < CAP) list[row_][pos_] = kv_;                     \
                }                                                               \
            }                                                                   \
    }

    LOADT(bA, 0);
    for (int t = 0; t < NTILES; t += 2) {
        LOADT(bB, t + 1);
        COMPB(bA, t);
        if (t + 2 < NTILES) LOADT(bA, t + 2);
        COMPB(bB, t + 1);
    }
    __syncthreads();   // lists complete

    if (tid < BM) {
        int c = cnt[tid];
        cand_cnt[m0 + tid] = (unsigned char)(c > CAP ? 255 : c);
        int n = c < CAP ? c : CAP;
        for (int j = 0; j < n; ++j) cand_k[(size_t)(m0 + tid) * CAP + j] = list[tid][j];
    }
#undef LOADT
#undef MFMA_TILE
#undef COMPA
#undef COMPB
}

// ---------------- kernel 3: rescore + gather / zq_st / per-row loss / idx ----------------
__global__ __launch_bounds__(256) void k_final(const float* __restrict__ z,
                                               const float* __restrict__ E,
                                               const float* __restrict__ En,
                                               const unsigned char* __restrict__ cand_cnt,
                                               const int* __restrict__ cand_k,
                                               float* __restrict__ out,
                                               float* __restrict__ rowloss) {
    __shared__ float zl[4][256];
    int wid  = threadIdx.x >> 6;
    int lane = threadIdx.x & 63;
    int m    = blockIdx.x * 4 + wid;

    const float* zr = z + (size_t)m * DDIM;
    const float4 zz = *(const float4*)&zr[lane * 4];

    int   c  = cand_cnt[m];
    float bv = -FLT_MAX;
    int   bk = 0x7fffffff;
    if (c != 255) {
        for (int j = 0; j < c; ++j) {
            int k = cand_k[(size_t)m * CAP + j];
            const float4 ee = *(const float4*)&En[(size_t)k * DDIM + lane * 4];
            float s = zz.x * ee.x + zz.y * ee.y + zz.z * ee.z + zz.w * ee.w;
#pragma unroll
            for (int off = 1; off < 64; off <<= 1) s += __shfl_xor(s, off);
            if (s > bv || (s == bv && k < bk)) { bv = s; bk = k; }
        }
    } else {
        // insurance fallback: wave-parallel full fp32 scan, z staged in LDS
        *(float4*)&zl[wid][lane * 4] = zz;
        asm volatile("s_waitcnt lgkmcnt(0)" ::: "memory");
        for (int kb = 0; kb < K_CODES; kb += 64) {
            int k = kb + lane;
            const float4* er = (const float4*)&En[(size_t)k * DDIM];
            float s0 = 0.f, s1 = 0.f, s2 = 0.f, s3 = 0.f;
#pragma unroll 8
            for (int d4 = 0; d4 < 64; ++d4) {
                float4 e  = er[d4];
                float4 zd = *(const float4*)&zl[wid][d4 * 4];
                s0 += zd.x * e.x; s1 += zd.y * e.y;
                s2 += zd.z * e.z; s3 += zd.w * e.w;
            }
            float s = (s0 + s1) + (s2 + s3);
            if (s > bv || (s == bv && k < bk)) { bv = s; bk = k; }
        }
#pragma unroll
        for (int off = 1; off < 64; off <<= 1) {
            float ov = __shfl_xor(bv, off);
            int   ok = __shfl_xor(bk, off);
            if (ov > bv || (ov == bv && ok < bk)) { bv = ov; bk = ok; }
        }
    }
    const int idx = bk;

    const float* er = E + (size_t)idx * DDIM;
    float zv[4], ev[4];
    float sz = 0.f, se = 0.f;
#pragma unroll
    for (int p = 0; p < 4; ++p) {
        zv[p] = zr[lane + 64 * p]; sz += zv[p] * zv[p];
        ev[p] = er[lane + 64 * p]; se += ev[p] * ev[p];
    }
#pragma unroll
    for (int off = 32; off >= 1; off >>= 1) {
        sz += __shfl_xor(sz, off);
        se += __shfl_xor(se, off);
    }
    float nz = fmaxf(sqrtf(sz), 1e-8f);
    float ne = fmaxf(sqrtf(se), 1e-8f);

    float rs = 0.f;
    float* zq = out + 1 + (size_t)m * DDIM;
#pragma unroll
    for (int p = 0; p < 4; ++p) {
        float zn = zv[p] / nz;
        float en = ev[p] / ne;
        float d  = en - zn;
        rs += d * d;
        zq[lane + 64 * p] = zv[p] + (ev[p] - zv[p]);
    }
#pragma unroll
    for (int off = 32; off >= 1; off >>= 1) rs += __shfl_xor(rs, off);

    if (lane == 0) {
        rowloss[m] = rs;
        out[1 + (size_t)M_ROWS * DDIM + m] = (float)idx;
    }
}

// ---------------- kernel 4: deterministic loss reduction ----------------
__global__ __launch_bounds__(256) void k_loss(const float* __restrict__ rowloss,
                                              float* __restrict__ out) {
    __shared__ double sm[256];
    double s = 0.0;
    for (int i = threadIdx.x; i < M_ROWS; i += 256) s += (double)rowloss[i];
    sm[threadIdx.x] = s;
    __syncthreads();
    for (int st = 128; st > 0; st >>= 1) {
        if (threadIdx.x < st) sm[threadIdx.x] += sm[threadIdx.x + st];
        __syncthreads();
    }
    if (threadIdx.x == 0) {
        float c = (float)(sm[0] / (double)((size_t)M_ROWS * DDIM));
        out[0] = c + 0.05f * c;
    }
}

extern "C" void kernel_launch(void* const* d_in, const int* in_sizes, int n_in,
                              void* d_out, int out_size, void* d_ws, size_t ws_size,
                              hipStream_t stream) {
    const float* z = (const float*)d_in[0];
    const float* E = (const float*)d_in[1];
    float* out = (float*)d_out;

    char* ws = (char*)d_ws;
    size_t off = 0;
    float*          En       = (float*)(ws + off);          off += (size_t)K_CODES * DDIM * 4;  // 8 MB
    unsigned short* En_b     = (unsigned short*)(ws + off); off += (size_t)K_CODES * DDIM * 2;  // 4 MB
    int*            cand_k   = (int*)(ws + off);            off += (size_t)M_ROWS * CAP * 4;    // 2 MB
    unsigned char*  cand_cnt = (unsigned char*)(ws + off);  off += (size_t)M_ROWS;              // 32 KB
    float*          rowloss  = (float*)(ws + off);

    k_norm_E<<<K_CODES / 4, 256, 0, stream>>>(E, En, En_b);
    k_cand<<<M_ROWS / BM, 256, 0, stream>>>(z, En_b, cand_cnt, cand_k);
    k_final<<<M_ROWS / 4, 256, 0, stream>>>(z, E, En, cand_cnt, cand_k, out, rowloss);
    k_loss<<<1, 256, 0, stream>>>(rowloss, out);
}

// Round 12
// 542.329 us; speedup vs baseline: 1.0620x; 1.0032x over previous
//
#include <hip/hip_runtime.h>
#include <float.h>
#include <math.h>
#include <stdint.h>

#define M_ROWS 32768
#define K_CODES 8192
#define DDIM 256
#define BM 64
#define BN 64
#define NTILES (K_CODES / BN)   // 128
#define DELTA 0.009f
#define CAP 16

typedef __attribute__((ext_vector_type(8))) short short8;
typedef __attribute__((ext_vector_type(4))) float f32x4;

__device__ inline unsigned short f2bf(float f) {
    unsigned u = __float_as_uint(f);
    return (unsigned short)((u + 0x7fffu + ((u >> 16) & 1u)) >> 16);
}
__device__ inline unsigned fkey(float f) {
    unsigned u = __float_as_uint(f);
    return u ^ ((unsigned)((int)u >> 31) | 0x80000000u);
}
__device__ inline float fkey_inv(unsigned k) {
    unsigned u = (k & 0x80000000u) ? (k ^ 0x80000000u) : ~k;
    return __uint_as_float(u);
}

// ---------------- kernel 1: normalize E -> En (fp32) + En_b (bf16) ----------------
__global__ __launch_bounds__(256) void k_norm_E(const float* __restrict__ E,
                                                float* __restrict__ En,
                                                unsigned short* __restrict__ En_b) {
    int wid  = threadIdx.x >> 6;
    int lane = threadIdx.x & 63;
    int row  = blockIdx.x * 4 + wid;
    const float* e = E + (size_t)row * DDIM;
    float v[4];
    float ssq = 0.f;
#pragma unroll
    for (int p = 0; p < 4; ++p) { v[p] = e[lane + 64 * p]; ssq += v[p] * v[p]; }
#pragma unroll
    for (int off = 32; off >= 1; off >>= 1) ssq += __shfl_xor(ssq, off);
    float inv = 1.f / fmaxf(sqrtf(ssq), 1e-8f);
    float* o = En + (size_t)row * DDIM;
    unsigned short* ob = En_b + (size_t)row * DDIM;
#pragma unroll
    for (int p = 0; p < 4; ++p) {
        float nv = v[p] * inv;
        o[lane + 64 * p]  = nv;
        ob[lane + 64 * p] = f2bf(nv);
    }
}

// ---------------- kernel 2: two-pass MFMA filter, B direct global->VGPR ----------
// 256 thr = 4 waves. Each wave owns 16 codes (wid) of the BN=64 tile and ALL
// BM=64 rows (af[4][8] = 128 VGPRs). B-fragments load straight from global
// into a register double buffer (bA/bB, 64 VGPRs) -- no LDS in the hot loop.
// __launch_bounds__(256, 1): R9-R11 showed the allocator caps at 128 VGPR for
// both (512,*) and (256,2) -> B-buffers spilled to scratch (WRITE_SIZE 36-70MB,
// ~2000 cyc/tile of L2 scratch roundtrips). (256,1) is satisfiable for a
// 4-wave block and doubles the cap to >=256 -> ~250 used, zero spill, and the
// runtime still fits 2 blocks/CU (8 waves, same TLP as R11).
// Pass A: register fmax -> exact row max. Pass B: recompute, emit >= max-DELTA.
__global__ __launch_bounds__(256, 1) void k_cand(
    const float* __restrict__ z,
    const unsigned short* __restrict__ En_b,
    unsigned char* __restrict__ cand_cnt,
    int* __restrict__ cand_k) {

    __shared__ unsigned rowmaxKey[BM];
    __shared__ int cnt[BM];
    __shared__ int list[BM][CAP];

    const int tid  = threadIdx.x;
    const int lane = tid & 63;
    const int wid  = tid >> 6;      // col-group 0..3
    const int lo   = lane & 15;
    const int hi   = lane >> 4;
    const int m0   = blockIdx.x * BM;

    if (tid < BM) { cnt[tid] = 0; rowmaxKey[tid] = 0u; }
    __syncthreads();

    // per-lane B base: code row = wid*16+lo, 16B sub-column hi within each 64B
    const char* bbase = (const char*)En_b + (size_t)(wid * 16 + lo) * 512 + hi * 16;

#define LOADT(buf, t)                                                           \
    {                                                                           \
        const char* bp_ = bbase + (size_t)(t) * (BN * 512);                     \
        _Pragma("unroll")                                                       \
        for (int ks_ = 0; ks_ < 8; ++ks_)                                       \
            buf[ks_] = *(const short8*)(bp_ + ks_ * 64);                        \
    }

    // issue first tile load early (covers af-setup latency)
    short8 bA[8], bB[8];
    LOADT(bA, 0);

    // ---- A fragments: load z fp32, normalize in-register, cvt bf16 ----
    // af[mi][ks]: row = mi*16 + lo (same rows for all 4 waves)
    short8 af[4][8];
#pragma unroll
    for (int mi = 0; mi < 4; ++mi) {
        const float* zr = z + (size_t)(m0 + mi * 16 + lo) * DDIM;
        float4 v[16];
        float ssq = 0.f;
#pragma unroll
        for (int ks = 0; ks < 8; ++ks) {
            int e0 = (ks * 4 + hi) * 8;
            v[2 * ks]     = *(const float4*)&zr[e0];
            v[2 * ks + 1] = *(const float4*)&zr[e0 + 4];
            float4 a = v[2 * ks], b = v[2 * ks + 1];
            ssq += a.x * a.x + a.y * a.y + a.z * a.z + a.w * a.w;
            ssq += b.x * b.x + b.y * b.y + b.z * b.z + b.w * b.w;
        }
        // 4 hi-lanes hold disjoint 64-element subsets of the row
        ssq += __shfl_xor(ssq, 16);
        ssq += __shfl_xor(ssq, 32);
        float inv = 1.f / fmaxf(sqrtf(ssq), 1e-8f);
#pragma unroll
        for (int ks = 0; ks < 8; ++ks) {
            float4 a = v[2 * ks], b = v[2 * ks + 1];
            short8 s8;
            s8[0] = (short)f2bf(a.x * inv); s8[1] = (short)f2bf(a.y * inv);
            s8[2] = (short)f2bf(a.z * inv); s8[3] = (short)f2bf(a.w * inv);
            s8[4] = (short)f2bf(b.x * inv); s8[5] = (short)f2bf(b.y * inv);
            s8[6] = (short)f2bf(b.z * inv); s8[7] = (short)f2bf(b.w * inv);
            af[mi][ks] = s8;
        }
    }

#define MFMA_TILE(buf, acc)                                                     \
    _Pragma("unroll")                                                           \
    for (int ks_ = 0; ks_ < 8; ++ks_) {                                         \
        _Pragma("unroll")                                                       \
        for (int mi_ = 0; mi_ < 4; ++mi_)                                       \
            acc[mi_] = __builtin_amdgcn_mfma_f32_16x16x32_bf16(                 \
                af[mi_][ks_], buf[ks_], acc[mi_], 0, 0, 0);                     \
    }

    // ================= PASS A: exact row max =================
    float pmax[16];
#pragma unroll
    for (int s = 0; s < 16; ++s) pmax[s] = -FLT_MAX;

#define COMPA(buf)                                                              \
    {                                                                           \
        f32x4 acc[4];                                                           \
        _Pragma("unroll") for (int mi_ = 0; mi_ < 4; ++mi_)                     \
            acc[mi_] = (f32x4){0.f, 0.f, 0.f, 0.f};                             \
        MFMA_TILE(buf, acc)                                                     \
        _Pragma("unroll") for (int mi_ = 0; mi_ < 4; ++mi_)                     \
            _Pragma("unroll") for (int r_ = 0; r_ < 4; ++r_)                    \
                pmax[mi_ * 4 + r_] = fmaxf(pmax[mi_ * 4 + r_], acc[mi_][r_]);   \
    }

    for (int t = 0; t < NTILES; t += 2) {
        LOADT(bB, t + 1);
        COMPA(bA);
        if (t + 2 < NTILES) LOADT(bA, t + 2);
        COMPA(bB);
    }

    // reduce row max across the 16 lo-lanes, publish via LDS atomicMax
#pragma unroll
    for (int s = 0; s < 16; ++s) {
        float w = pmax[s];
        w = fmaxf(w, __shfl_xor(w, 1));
        w = fmaxf(w, __shfl_xor(w, 2));
        w = fmaxf(w, __shfl_xor(w, 4));
        w = fmaxf(w, __shfl_xor(w, 8));
        if (lo == 0) {
            int row = (s >> 2) * 16 + hi * 4 + (s & 3);
            atomicMax(&rowmaxKey[row], fkey(w));
        }
    }
    __syncthreads();   // all waves' maxima published

    float thr[16];
#pragma unroll
    for (int s = 0; s < 16; ++s) {
        int row = (s >> 2) * 16 + hi * 4 + (s & 3);
        thr[s] = fkey_inv(rowmaxKey[row]) - DELTA;
    }

    // ================= PASS B: emit candidates =================
#define COMPB(buf, t)                                                           \
    {                                                                           \
        f32x4 acc[4];                                                           \
        _Pragma("unroll") for (int mi_ = 0; mi_ < 4; ++mi_)                     \
            acc[mi_] = (f32x4){0.f, 0.f, 0.f, 0.f};                             \
        MFMA_TILE(buf, acc)                                                     \
        const int kv_ = (t) * BN + wid * 16 + lo;                               \
        _Pragma("unroll") for (int mi_ = 0; mi_ < 4; ++mi_)                     \
            _Pragma("unroll") for (int r_ = 0; r_ < 4; ++r_) {                  \
                if (acc[mi_][r_] >= thr[mi_ * 4 + r_]) {                        \
                    int row_ = mi_ * 16 + hi * 4 + r_;                          \
                    int pos_ = atomicAdd(&cnt[row_], 1);                        \
                    if (pos_ < CAP) list[row_][pos_] = kv_;                     \
                }                                                               \
            }                                                                   \
    }

    LOADT(bA, 0);
    for (int t = 0; t < NTILES; t += 2) {
        LOADT(bB, t + 1);
        COMPB(bA, t);
        if (t + 2 < NTILES) LOADT(bA, t + 2);
        COMPB(bB, t + 1);
    }
    __syncthreads();   // lists complete

    if (tid < BM) {
        int c = cnt[tid];
        cand_cnt[m0 + tid] = (unsigned char)(c > CAP ? 255 : c);
        int n = c < CAP ? c : CAP;
        for (int j = 0; j < n; ++j) cand_k[(size_t)(m0 + tid) * CAP + j] = list[tid][j];
    }
#undef LOADT
#undef MFMA_TILE
#undef COMPA
#undef COMPB
}

// ---------------- kernel 3: rescore + gather / zq_st / per-row loss / idx ----------------
__global__ __launch_bounds__(256) void k_final(const float* __restrict__ z,
                                               const float* __restrict__ E,
                                               const float* __restrict__ En,
                                               const unsigned char* __restrict__ cand_cnt,
                                               const int* __restrict__ cand_k,
                                               float* __restrict__ out,
                                               float* __restrict__ rowloss) {
    __shared__ float zl[4][256];
    int wid  = threadIdx.x >> 6;
    int lane = threadIdx.x & 63;
    int m    = blockIdx.x * 4 + wid;

    const float* zr = z + (size_t)m * DDIM;
    const float4 zz = *(const float4*)&zr[lane * 4];

    int   c  = cand_cnt[m];
    float bv = -FLT_MAX;
    int   bk = 0x7fffffff;
    if (c != 255) {
        for (int j = 0; j < c; ++j) {
            int k = cand_k[(size_t)m * CAP + j];
            const float4 ee = *(const float4*)&En[(size_t)k * DDIM + lane * 4];
            float s = zz.x * ee.x + zz.y * ee.y + zz.z * ee.z + zz.w * ee.w;
#pragma unroll
            for (int off = 1; off < 64; off <<= 1) s += __shfl_xor(s, off);
            if (s > bv || (s == bv && k < bk)) { bv = s; bk = k; }
        }
    } else {
        // insurance fallback: wave-parallel full fp32 scan, z staged in LDS
        *(float4*)&zl[wid][lane * 4] = zz;
        asm volatile("s_waitcnt lgkmcnt(0)" ::: "memory");
        for (int kb = 0; kb < K_CODES; kb += 64) {
            int k = kb + lane;
            const float4* er = (const float4*)&En[(size_t)k * DDIM];
            float s0 = 0.f, s1 = 0.f, s2 = 0.f, s3 = 0.f;
#pragma unroll 8
            for (int d4 = 0; d4 < 64; ++d4) {
                float4 e  = er[d4];
                float4 zd = *(const float4*)&zl[wid][d4 * 4];
                s0 += zd.x * e.x; s1 += zd.y * e.y;
                s2 += zd.z * e.z; s3 += zd.w * e.w;
            }
            float s = (s0 + s1) + (s2 + s3);
            if (s > bv || (s == bv && k < bk)) { bv = s; bk = k; }
        }
#pragma unroll
        for (int off = 1; off < 64; off <<= 1) {
            float ov = __shfl_xor(bv, off);
            int   ok = __shfl_xor(bk, off);
            if (ov > bv || (ov == bv && ok < bk)) { bv = ov; bk = ok; }
        }
    }
    const int idx = bk;

    const float* er = E + (size_t)idx * DDIM;
    float zv[4], ev[4];
    float sz = 0.f, se = 0.f;
#pragma unroll
    for (int p = 0; p < 4; ++p) {
        zv[p] = zr[lane + 64 * p]; sz += zv[p] * zv[p];
        ev[p] = er[lane + 64 * p]; se += ev[p] * ev[p];
    }
#pragma unroll
    for (int off = 32; off >= 1; off >>= 1) {
        sz += __shfl_xor(sz, off);
        se += __shfl_xor(se, off);
    }
    float nz = fmaxf(sqrtf(sz), 1e-8f);
    float ne = fmaxf(sqrtf(se), 1e-8f);

    float rs = 0.f;
    float* zq = out + 1 + (size_t)m * DDIM;
#pragma unroll
    for (int p = 0; p < 4; ++p) {
        float zn = zv[p] / nz;
        float en = ev[p] / ne;
        float d  = en - zn;
        rs += d * d;
        zq[lane + 64 * p] = zv[p] + (ev[p] - zv[p]);
    }
#pragma unroll
    for (int off = 32; off >= 1; off >>= 1) rs += __shfl_xor(rs, off);

    if (lane == 0) {
        rowloss[m] = rs;
        out[1 + (size_t)M_ROWS * DDIM + m] = (float)idx;
    }
}

// ---------------- kernel 4: deterministic loss reduction ----------------
__global__ __launch_bounds__(256) void k_loss(const float* __restrict__ rowloss,
                                              float* __restrict__ out) {
    __shared__ double sm[256];
    double s = 0.0;
    for (int i = threadIdx.x; i < M_ROWS; i += 256) s += (double)rowloss[i];
    sm[threadIdx.x] = s;
    __syncthreads();
    for (int st = 128; st > 0; st >>= 1) {
        if (threadIdx.x < st) sm[threadIdx.x] += sm[threadIdx.x + st];
        __syncthreads();
    }
    if (threadIdx.x == 0) {
        float c = (float)(sm[0] / (double)((size_t)M_ROWS * DDIM));
        out[0] = c + 0.05f * c;
    }
}

extern "C" void kernel_launch(void* const* d_in, const int* in_sizes, int n_in,
                              void* d_out, int out_size, void* d_ws, size_t ws_size,
                              hipStream_t stream) {
    const float* z = (const float*)d_in[0];
    const float* E = (const float*)d_in[1];
    float* out = (float*)d_out;

    char* ws = (char*)d_ws;
    size_t off = 0;
    float*          En       = (float*)(ws + off);          off += (size_t)K_CODES * DDIM * 4;  // 8 MB
    unsigned short* En_b     = (unsigned short*)(ws + off); off += (size_t)K_CODES * DDIM * 2;  // 4 MB
    int*            cand_k   = (int*)(ws + off);            off += (size_t)M_ROWS * CAP * 4;    // 2 MB
    unsigned char*  cand_cnt = (unsigned char*)(ws + off);  off += (size_t)M_ROWS;              // 32 KB
    float*          rowloss  = (float*)(ws + off);

    k_norm_E<<<K_CODES / 4, 256, 0, stream>>>(E, En, En_b);
    k_cand<<<M_ROWS / BM, 256, 0, stream>>>(z, En_b, cand_cnt, cand_k);
    k_final<<<M_ROWS / 4, 256, 0, stream>>>(z, E, En, cand_cnt, cand_k, out, rowloss);
    k_loss<<<1, 256, 0, stream>>>(rowloss, out);
}

// Round 13
// 494.495 us; speedup vs baseline: 1.1648x; 1.0967x over previous
//
#include <hip/hip_runtime.h>
#include <float.h>
#include <math.h>
#include <stdint.h>

#define M_ROWS 32768
#define K_CODES 8192
#define DDIM 256
#define BM 128
#define BN 64
#define NTILES (K_CODES / BN)   // 128
#define DELTA 0.009f
#define CAP 16

typedef __attribute__((ext_vector_type(8))) short short8;
typedef __attribute__((ext_vector_type(4))) float f32x4;

__device__ inline unsigned short f2bf(float f) {
    unsigned u = __float_as_uint(f);
    return (unsigned short)((u + 0x7fffu + ((u >> 16) & 1u)) >> 16);
}
__device__ inline unsigned fkey(float f) {
    unsigned u = __float_as_uint(f);
    return u ^ ((unsigned)((int)u >> 31) | 0x80000000u);
}
__device__ inline float fkey_inv(unsigned k) {
    unsigned u = (k & 0x80000000u) ? (k ^ 0x80000000u) : ~k;
    return __uint_as_float(u);
}

#define GLOAD16(gsrc, ldst)                                                     \
    __builtin_amdgcn_global_load_lds(                                           \
        (const __attribute__((address_space(1))) void*)(gsrc),                  \
        (__attribute__((address_space(3))) void*)(ldst), 16, 0, 0)

// ---------------- kernel 1: normalize E -> En (fp32) + En_b (bf16) ----------------
__global__ __launch_bounds__(256) void k_norm_E(const float* __restrict__ E,
                                                float* __restrict__ En,
                                                unsigned short* __restrict__ En_b) {
    int wid  = threadIdx.x >> 6;
    int lane = threadIdx.x & 63;
    int row  = blockIdx.x * 4 + wid;
    const float* e = E + (size_t)row * DDIM;
    float v[4];
    float ssq = 0.f;
#pragma unroll
    for (int p = 0; p < 4; ++p) { v[p] = e[lane + 64 * p]; ssq += v[p] * v[p]; }
#pragma unroll
    for (int off = 32; off >= 1; off >>= 1) ssq += __shfl_xor(ssq, off);
    float inv = 1.f / fmaxf(sqrtf(ssq), 1e-8f);
    float* o = En + (size_t)row * DDIM;
    unsigned short* ob = En_b + (size_t)row * DDIM;
#pragma unroll
    for (int p = 0; p < 4; ++p) {
        float nv = v[p] * inv;
        o[lane + 64 * p]  = nv;
        ob[lane + 64 * p] = f2bf(nv);
    }
}

// ---------------- kernel 2: two-pass MFMA filter, BM=128, 1 block/CU ----------
// 256 thr = 4 waves: wr=wid>>1 (64-row half), wc=wid&1 (32-col half of BN=64).
// af[4][8] = 128 VGPR (64 rows/wave); each B ds_read feeds 4 MFMAs.
// __launch_bounds__(256,1) opens the allocator (R12: proved >128) -> ~220 VGPR,
// no spill. Grid 256 = exactly 1 block/CU -> minimal L2 B-traffic (8 MB/CU).
// B: LDS triple-buffer (3x32KB), global_load_lds depth-2, counted vmcnt(8),
// raw s_barrier per phase (R6/R7-proven skeleton, pre-swizzled source).
// Pass A: register fmax -> exact row max. Pass B: recompute, emit >= max-DELTA.
__global__ __launch_bounds__(256, 1) void k_cand(
    const float* __restrict__ z,
    const unsigned short* __restrict__ En_b,
    unsigned char* __restrict__ cand_cnt,
    int* __restrict__ cand_k) {

    __shared__ __attribute__((aligned(16))) char Bs[3][32768];   // 96 KB
    __shared__ unsigned rowmaxKey[BM];
    __shared__ int cnt[BM];
    __shared__ int list[BM][CAP];                                 // 8 KB

    const int tid  = threadIdx.x;
    const int lane = tid & 63;
    const int wid  = tid >> 6;      // wave 0..3
    const int wr   = wid >> 1;      // row half
    const int wc   = wid & 1;       // col half
    const int lo   = lane & 15;
    const int hi   = lane >> 4;
    const int m0   = blockIdx.x * BM;

    if (tid < BM) { cnt[tid] = 0; rowmaxKey[tid] = 0u; }

    const char* eb = (const char*)En_b;

    // stage tile `ktile` (64 codes x 512B = 32KB = 32 chunks); 8 chunks/wave
    auto stage = [&](int ktile, char* bufp) {
#pragma unroll
        for (int i = 0; i < 8; ++i) {
            int chunk = i * 4 + wid;            // 0..31
            int G   = chunk * 64 + lane;
            int row = G >> 5;                   // 0..63
            int g   = (G & 31) ^ (row & 7);
            GLOAD16(eb + (size_t)(ktile * BN + row) * 512 + g * 16, bufp + chunk * 1024);
        }
    };

    // prologue: issue tiles 0,1 (latency covered by af-setup below)
    stage(0, &Bs[0][0]);
    stage(1, &Bs[1][0]);

    // ---- A fragments: load z fp32, normalize in-register, cvt bf16 ----
    // af[mi][ks]: row = wr*64 + mi*16 + lo
    short8 af[4][8];
#pragma unroll
    for (int mi = 0; mi < 4; ++mi) {
        const float* zr = z + (size_t)(m0 + wr * 64 + mi * 16 + lo) * DDIM;
        float4 v[16];
        float ssq = 0.f;
#pragma unroll
        for (int ks = 0; ks < 8; ++ks) {
            int e0 = (ks * 4 + hi) * 8;
            v[2 * ks]     = *(const float4*)&zr[e0];
            v[2 * ks + 1] = *(const float4*)&zr[e0 + 4];
            float4 a = v[2 * ks], b = v[2 * ks + 1];
            ssq += a.x * a.x + a.y * a.y + a.z * a.z + a.w * a.w;
            ssq += b.x * b.x + b.y * b.y + b.z * b.z + b.w * b.w;
        }
        // 4 hi-lanes hold disjoint 64-element subsets of the row
        ssq += __shfl_xor(ssq, 16);
        ssq += __shfl_xor(ssq, 32);
        float inv = 1.f / fmaxf(sqrtf(ssq), 1e-8f);
#pragma unroll
        for (int ks = 0; ks < 8; ++ks) {
            float4 a = v[2 * ks], b = v[2 * ks + 1];
            short8 s8;
            s8[0] = (short)f2bf(a.x * inv); s8[1] = (short)f2bf(a.y * inv);
            s8[2] = (short)f2bf(a.z * inv); s8[3] = (short)f2bf(a.w * inv);
            s8[4] = (short)f2bf(b.x * inv); s8[5] = (short)f2bf(b.y * inv);
            s8[6] = (short)f2bf(b.z * inv); s8[7] = (short)f2bf(b.w * inv);
            af[mi][ks] = s8;
        }
    }
    __syncthreads();   // init visible; drains prologue staging (one-time cost)

    const int brow0 = wc * 32 + lo;
    const int brow1 = wc * 32 + 16 + lo;
    const int bsw0  = brow0 & 7;
    const int bsw1  = brow1 & 7;

#define COMPUTE_TILE(acc, Bc)                                                   \
    _Pragma("unroll")                                                           \
    for (int ks_ = 0; ks_ < 8; ++ks_) {                                         \
        short8 bf0_ = *(const short8*)&Bc[brow0 * 256 + (((ks_ * 4 + hi) ^ bsw0)) * 8]; \
        short8 bf1_ = *(const short8*)&Bc[brow1 * 256 + (((ks_ * 4 + hi) ^ bsw1)) * 8]; \
        _Pragma("unroll")                                                       \
        for (int mi_ = 0; mi_ < 4; ++mi_) {                                     \
            acc[mi_][0] = __builtin_amdgcn_mfma_f32_16x16x32_bf16(              \
                af[mi_][ks_], bf0_, acc[mi_][0], 0, 0, 0);                      \
            acc[mi_][1] = __builtin_amdgcn_mfma_f32_16x16x32_bf16(              \
                af[mi_][ks_], bf1_, acc[mi_][1], 0, 0, 0);                      \
        }                                                                       \
    }

    // ================= PASS A: exact row max =================
    float pmax[16];
#pragma unroll
    for (int s = 0; s < 16; ++s) pmax[s] = -FLT_MAX;

    for (int t = 0; t < NTILES; ++t) {
        if (t < NTILES - 1) asm volatile("s_waitcnt vmcnt(8)" ::: "memory");
        else                asm volatile("s_waitcnt vmcnt(0)" ::: "memory");
        __builtin_amdgcn_s_barrier();
        __builtin_amdgcn_sched_barrier(0);
        if (t + 2 < NTILES) stage(t + 2, &Bs[(t + 2) % 3][0]);

        f32x4 acc[4][2];
#pragma unroll
        for (int mi = 0; mi < 4; ++mi) {
            acc[mi][0] = (f32x4){0.f, 0.f, 0.f, 0.f};
            acc[mi][1] = (f32x4){0.f, 0.f, 0.f, 0.f};
        }
        const unsigned short* Bc = (const unsigned short*)&Bs[t % 3][0];
        COMPUTE_TILE(acc, Bc)
#pragma unroll
        for (int mi = 0; mi < 4; ++mi)
#pragma unroll
            for (int r = 0; r < 4; ++r)
                pmax[mi * 4 + r] = fmaxf(pmax[mi * 4 + r],
                                         fmaxf(acc[mi][0][r], acc[mi][1][r]));
    }

    // reduce row max across the 16 lo-lanes, publish via LDS atomicMax
#pragma unroll
    for (int s = 0; s < 16; ++s) {
        float w = pmax[s];
        w = fmaxf(w, __shfl_xor(w, 1));
        w = fmaxf(w, __shfl_xor(w, 2));
        w = fmaxf(w, __shfl_xor(w, 4));
        w = fmaxf(w, __shfl_xor(w, 8));
        if (lo == 0) {
            int row = wr * 64 + (s >> 2) * 16 + hi * 4 + (s & 3);
            atomicMax(&rowmaxKey[row], fkey(w));
        }
    }
    __syncthreads();   // all waves' maxima published (full drain, once)

    float thr[16];
#pragma unroll
    for (int s = 0; s < 16; ++s) {
        int row = wr * 64 + (s >> 2) * 16 + hi * 4 + (s & 3);
        thr[s] = fkey_inv(rowmaxKey[row]) - DELTA;
    }

    // ================= PASS B: emit candidates =================
    stage(0, &Bs[0][0]);
    stage(1, &Bs[1][0]);

    for (int t = 0; t < NTILES; ++t) {
        if (t < NTILES - 1) asm volatile("s_waitcnt vmcnt(8)" ::: "memory");
        else                asm volatile("s_waitcnt vmcnt(0)" ::: "memory");
        __builtin_amdgcn_s_barrier();
        __builtin_amdgcn_sched_barrier(0);
        if (t + 2 < NTILES) stage(t + 2, &Bs[(t + 2) % 3][0]);

        f32x4 acc[4][2];
#pragma unroll
        for (int mi = 0; mi < 4; ++mi) {
            acc[mi][0] = (f32x4){0.f, 0.f, 0.f, 0.f};
            acc[mi][1] = (f32x4){0.f, 0.f, 0.f, 0.f};
        }
        const unsigned short* Bc = (const unsigned short*)&Bs[t % 3][0];
        COMPUTE_TILE(acc, Bc)

        const int kt = t * BN;
#pragma unroll
        for (int mi = 0; mi < 4; ++mi)
#pragma unroll
            for (int r = 0; r < 4; ++r) {
                int s = mi * 4 + r;
#pragma unroll
                for (int nj = 0; nj < 2; ++nj) {
                    if (acc[mi][nj][r] >= thr[s]) {
                        int row = wr * 64 + mi * 16 + hi * 4 + r;
                        int pos = atomicAdd(&cnt[row], 1);
                        if (pos < CAP) list[row][pos] = kt + wc * 32 + nj * 16 + lo;
                    }
                }
            }
    }
    __syncthreads();   // lists complete

    if (tid < BM) {
        int c = cnt[tid];
        cand_cnt[m0 + tid] = (unsigned char)(c > CAP ? 255 : c);
        int n = c < CAP ? c : CAP;
        for (int j = 0; j < n; ++j) cand_k[(size_t)(m0 + tid) * CAP + j] = list[tid][j];
    }
#undef COMPUTE_TILE
}

// ---------------- kernel 3: rescore + gather / zq_st / per-row loss / idx ----------------
__global__ __launch_bounds__(256) void k_final(const float* __restrict__ z,
                                               const float* __restrict__ E,
                                               const float* __restrict__ En,
                                               const unsigned char* __restrict__ cand_cnt,
                                               const int* __restrict__ cand_k,
                                               float* __restrict__ out,
                                               float* __restrict__ rowloss) {
    __shared__ float zl[4][256];
    int wid  = threadIdx.x >> 6;
    int lane = threadIdx.x & 63;
    int m    = blockIdx.x * 4 + wid;

    const float* zr = z + (size_t)m * DDIM;
    const float4 zz = *(const float4*)&zr[lane * 4];

    int   c  = cand_cnt[m];
    float bv = -FLT_MAX;
    int   bk = 0x7fffffff;
    if (c != 255) {
        for (int j = 0; j < c; ++j) {
            int k = cand_k[(size_t)m * CAP + j];
            const float4 ee = *(const float4*)&En[(size_t)k * DDIM + lane * 4];
            float s = zz.x * ee.x + zz.y * ee.y + zz.z * ee.z + zz.w * ee.w;
#pragma unroll
            for (int off = 1; off < 64; off <<= 1) s += __shfl_xor(s, off);
            if (s > bv || (s == bv && k < bk)) { bv = s; bk = k; }
        }
    } else {
        // insurance fallback: wave-parallel full fp32 scan, z staged in LDS
        *(float4*)&zl[wid][lane * 4] = zz;
        asm volatile("s_waitcnt lgkmcnt(0)" ::: "memory");
        for (int kb = 0; kb < K_CODES; kb += 64) {
            int k = kb + lane;
            const float4* er = (const float4*)&En[(size_t)k * DDIM];
            float s0 = 0.f, s1 = 0.f, s2 = 0.f, s3 = 0.f;
#pragma unroll 8
            for (int d4 = 0; d4 < 64; ++d4) {
                float4 e  = er[d4];
                float4 zd = *(const float4*)&zl[wid][d4 * 4];
                s0 += zd.x * e.x; s1 += zd.y * e.y;
                s2 += zd.z * e.z; s3 += zd.w * e.w;
            }
            float s = (s0 + s1) + (s2 + s3);
            if (s > bv || (s == bv && k < bk)) { bv = s; bk = k; }
        }
#pragma unroll
        for (int off = 1; off < 64; off <<= 1) {
            float ov = __shfl_xor(bv, off);
            int   ok = __shfl_xor(bk, off);
            if (ov > bv || (ov == bv && ok < bk)) { bv = ov; bk = ok; }
        }
    }
    const int idx = bk;

    const float* er = E + (size_t)idx * DDIM;
    float zv[4], ev[4];
    float sz = 0.f, se = 0.f;
#pragma unroll
    for (int p = 0; p < 4; ++p) {
        zv[p] = zr[lane + 64 * p]; sz += zv[p] * zv[p];
        ev[p] = er[lane + 64 * p]; se += ev[p] * ev[p];
    }
#pragma unroll
    for (int off = 32; off >= 1; off >>= 1) {
        sz += __shfl_xor(sz, off);
        se += __shfl_xor(se, off);
    }
    float nz = fmaxf(sqrtf(sz), 1e-8f);
    float ne = fmaxf(sqrtf(se), 1e-8f);

    float rs = 0.f;
    float* zq = out + 1 + (size_t)m * DDIM;
#pragma unroll
    for (int p = 0; p < 4; ++p) {
        float zn = zv[p] / nz;
        float en = ev[p] / ne;
        float d  = en - zn;
        rs += d * d;
        zq[lane + 64 * p] = zv[p] + (ev[p] - zv[p]);
    }
#pragma unroll
    for (int off = 32; off >= 1; off >>= 1) rs += __shfl_xor(rs, off);

    if (lane == 0) {
        rowloss[m] = rs;
        out[1 + (size_t)M_ROWS * DDIM + m] = (float)idx;
    }
}

// ---------------- kernel 4: deterministic loss reduction ----------------
__global__ __launch_bounds__(256) void k_loss(const float* __restrict__ rowloss,
                                              float* __restrict__ out) {
    __shared__ double sm[256];
    double s = 0.0;
    for (int i = threadIdx.x; i < M_ROWS; i += 256) s += (double)rowloss[i];
    sm[threadIdx.x] = s;
    __syncthreads();
    for (int st = 128; st > 0; st >>= 1) {
        if (threadIdx.x < st) sm[threadIdx.x] += sm[threadIdx.x + st];
        __syncthreads();
    }
    if (threadIdx.x == 0) {
        float c = (float)(sm[0] / (double)((size_t)M_ROWS * DDIM));
        out[0] = c + 0.05f * c;
    }
}

extern "C" void kernel_launch(void* const* d_in, const int* in_sizes, int n_in,
                              void* d_out, int out_size, void* d_ws, size_t ws_size,
                              hipStream_t stream) {
    const float* z = (const float*)d_in[0];
    const float* E = (const float*)d_in[1];
    float* out = (float*)d_out;

    char* ws = (char*)d_ws;
    size_t off = 0;
    float*          En       = (float*)(ws + off);          off += (size_t)K_CODES * DDIM * 4;  // 8 MB
    unsigned short* En_b     = (unsigned short*)(ws + off); off += (size_t)K_CODES * DDIM * 2;  // 4 MB
    int*            cand_k   = (int*)(ws + off);            off += (size_t)M_ROWS * CAP * 4;    // 2 MB
    unsigned char*  cand_cnt = (unsigned char*)(ws + off);  off += (size_t)M_ROWS;              // 32 KB
    float*          rowloss  = (float*)(ws + off);

    k_norm_E<<<K_CODES / 4, 256, 0, stream>>>(E, En, En_b);
    k_cand<<<M_ROWS / BM, 256, 0, stream>>>(z, En_b, cand_cnt, cand_k);
    k_final<<<M_ROWS / 4, 256, 0, stream>>>(z, E, En, cand_cnt, cand_k, out, rowloss);
    k_loss<<<1, 256, 0, stream>>>(rowloss, out);
}

// Round 14
// 426.992 us; speedup vs baseline: 1.3489x; 1.1581x over previous
//
#include <hip/hip_runtime.h>
#include <float.h>
#include <math.h>
#include <stdint.h>

#define M_ROWS 32768
#define K_CODES 8192
#define DDIM 256
#define BM 64
#define BN 64
#define NTILES (K_CODES / BN)   // 128
#define DELTA 0.009f
#define CAP 16
#define FLAGBIT 0x10000

typedef __attribute__((ext_vector_type(8))) short short8;
typedef __attribute__((ext_vector_type(4))) float f32x4;

__device__ inline unsigned short f2bf(float f) {
    unsigned u = __float_as_uint(f);
    return (unsigned short)((u + 0x7fffu + ((u >> 16) & 1u)) >> 16);
}
__device__ inline unsigned fkey(float f) {
    unsigned u = __float_as_uint(f);
    return u ^ ((unsigned)((int)u >> 31) | 0x80000000u);
}
__device__ inline float fkey_inv(unsigned k) {
    unsigned u = (k & 0x80000000u) ? (k ^ 0x80000000u) : ~k;
    return __uint_as_float(u);
}

#define GLOAD16(gsrc, ldst)                                                     \
    __builtin_amdgcn_global_load_lds(                                           \
        (const __attribute__((address_space(1))) void*)(gsrc),                  \
        (__attribute__((address_space(3))) void*)(ldst), 16, 0, 0)

// ---------------- kernel 1: normalize E -> En (fp32) + En_b (bf16) ----------------
__global__ __launch_bounds__(256) void k_norm_E(const float* __restrict__ E,
                                                float* __restrict__ En,
                                                unsigned short* __restrict__ En_b) {
    int wid  = threadIdx.x >> 6;
    int lane = threadIdx.x & 63;
    int row  = blockIdx.x * 4 + wid;
    const float* e = E + (size_t)row * DDIM;
    float v[4];
    float ssq = 0.f;
#pragma unroll
    for (int p = 0; p < 4; ++p) { v[p] = e[lane + 64 * p]; ssq += v[p] * v[p]; }
#pragma unroll
    for (int off = 32; off >= 1; off >>= 1) ssq += __shfl_xor(ssq, off);
    float inv = 1.f / fmaxf(sqrtf(ssq), 1e-8f);
    float* o = En + (size_t)row * DDIM;
    unsigned short* ob = En_b + (size_t)row * DDIM;
#pragma unroll
    for (int p = 0; p < 4; ++p) {
        float nv = v[p] * inv;
        o[lane + 64 * p]  = nv;
        ob[lane + 64 * p] = f2bf(nv);
    }
}

// ---------------- kernel 2: SINGLE-pass MFMA filter with per-lane top-2 ----------
// 256 thr = 4 waves, BM=64 rows, BN=64-code tiles; wave wid owns cols wid*16+lo,
// ALL 64 rows in registers (af[4][8] = 128 VGPR -> each B ds_read feeds 4 MFMAs).
// Grid 512 = 2 blocks/CU (LDS 69KB<=80, ~210 VGPR<=256 at (256,1)) -> 2 waves/SIMD.
// Per (slot,lane) stream of 128 values: track v1/k1/v2 branchlessly. End: exact
// bf16 rowmax -> thr = max-DELTA; emit k1 if v1>=thr; emit FLAG(colbase) if
// v2>=thr (a 3rd unseen value could hide in [thr,v2] -> k_final rescans that
// stream's 128 codes exactly). Provably contains the fp32 argmax.
__global__ __launch_bounds__(256, 1) void k_cand(
    const float* __restrict__ z,
    const unsigned short* __restrict__ En_b,
    unsigned char* __restrict__ cand_cnt,
    int* __restrict__ cand_k) {

    __shared__ __attribute__((aligned(16))) char Bs[2][32768];   // 64 KB
    __shared__ unsigned rowmaxKey[BM];
    __shared__ int cnt[BM];
    __shared__ int list[BM][CAP];                                 // 4 KB

    const int tid  = threadIdx.x;
    const int lane = tid & 63;
    const int wid  = tid >> 6;      // col-group 0..3
    const int lo   = lane & 15;
    const int hi   = lane >> 4;
    const int m0   = blockIdx.x * BM;

    if (tid < BM) { cnt[tid] = 0; rowmaxKey[tid] = 0u; }

    const char* eb = (const char*)En_b;

    // stage tile ktile (64 codes x 512B = 32 chunks of 1KB); 8 chunks/wave
    auto stage = [&](int ktile, char* bufp) {
#pragma unroll
        for (int i = 0; i < 8; ++i) {
            int chunk = i * 4 + wid;            // 0..31
            int G   = chunk * 64 + lane;
            int row = G >> 5;                   // 0..63
            int g   = (G & 31) ^ (row & 7);
            GLOAD16(eb + (size_t)(ktile * BN + row) * 512 + g * 16, bufp + chunk * 1024);
        }
    };

    stage(0, &Bs[0][0]);   // in flight during af setup

    // ---- A fragments: z fp32 -> normalize in-register -> bf16 ----
    short8 af[4][8];
#pragma unroll
    for (int mi = 0; mi < 4; ++mi) {
        const float* zr = z + (size_t)(m0 + mi * 16 + lo) * DDIM;
        float4 v[16];
        float ssq = 0.f;
#pragma unroll
        for (int ks = 0; ks < 8; ++ks) {
            int e0 = (ks * 4 + hi) * 8;
            v[2 * ks]     = *(const float4*)&zr[e0];
            v[2 * ks + 1] = *(const float4*)&zr[e0 + 4];
            float4 a = v[2 * ks], b = v[2 * ks + 1];
            ssq += a.x * a.x + a.y * a.y + a.z * a.z + a.w * a.w;
            ssq += b.x * b.x + b.y * b.y + b.z * b.z + b.w * b.w;
        }
        ssq += __shfl_xor(ssq, 16);
        ssq += __shfl_xor(ssq, 32);
        float inv = 1.f / fmaxf(sqrtf(ssq), 1e-8f);
#pragma unroll
        for (int ks = 0; ks < 8; ++ks) {
            float4 a = v[2 * ks], b = v[2 * ks + 1];
            short8 s8;
            s8[0] = (short)f2bf(a.x * inv); s8[1] = (short)f2bf(a.y * inv);
            s8[2] = (short)f2bf(a.z * inv); s8[3] = (short)f2bf(a.w * inv);
            s8[4] = (short)f2bf(b.x * inv); s8[5] = (short)f2bf(b.y * inv);
            s8[6] = (short)f2bf(b.z * inv); s8[7] = (short)f2bf(b.w * inv);
            af[mi][ks] = s8;
        }
    }

    // per-slot stream state (slot s = mi*4+r; row = mi*16 + hi*4 + r)
    float v1[16], v2[16];
    int   k1[16];
#pragma unroll
    for (int s = 0; s < 16; ++s) { v1[s] = -FLT_MAX; v2[s] = -FLT_MAX; k1[s] = 0; }

    __syncthreads();   // init visible + stage(0) drained

    const int brow = wid * 16 + lo;
    const int bsw  = brow & 7;

    for (int t = 0; t < NTILES; ++t) {
        if (t + 1 < NTILES) stage(t + 1, &Bs[(t + 1) & 1][0]);

        f32x4 acc[4];
#pragma unroll
        for (int mi = 0; mi < 4; ++mi) acc[mi] = (f32x4){0.f, 0.f, 0.f, 0.f};
        const unsigned short* Bc = (const unsigned short*)&Bs[t & 1][0];
#pragma unroll
        for (int ks = 0; ks < 8; ++ks) {
            short8 bf = *(const short8*)&Bc[brow * 256 + (((ks * 4 + hi) ^ bsw)) * 8];
#pragma unroll
            for (int mi = 0; mi < 4; ++mi)
                acc[mi] = __builtin_amdgcn_mfma_f32_16x16x32_bf16(af[mi][ks], bf, acc[mi], 0, 0, 0);
        }

        const int kv = t * BN + wid * 16 + lo;
#pragma unroll
        for (int mi = 0; mi < 4; ++mi)
#pragma unroll
            for (int r = 0; r < 4; ++r) {
                int s = mi * 4 + r;
                float v = acc[mi][r];
                v2[s] = fmaxf(v2[s], fminf(v1[s], v));    // streaming 2nd max
                k1[s] = (v > v1[s]) ? kv : k1[s];
                v1[s] = fmaxf(v1[s], v);
            }

        __syncthreads();   // stage(t+1) complete + buffer t free for t+2
    }

    // ---- exact bf16 row max: reduce v1 over 16 lo-lanes, cross-wave via LDS ----
#pragma unroll
    for (int s = 0; s < 16; ++s) {
        float w = v1[s];
        w = fmaxf(w, __shfl_xor(w, 1));
        w = fmaxf(w, __shfl_xor(w, 2));
        w = fmaxf(w, __shfl_xor(w, 4));
        w = fmaxf(w, __shfl_xor(w, 8));
        if (lo == 0) {
            int row = (s >> 2) * 16 + hi * 4 + (s & 3);
            atomicMax(&rowmaxKey[row], fkey(w));
        }
    }
    __syncthreads();

    // ---- emit candidates + flag entries ----
#pragma unroll
    for (int s = 0; s < 16; ++s) {
        int row = (s >> 2) * 16 + hi * 4 + (s & 3);
        float thr = fkey_inv(rowmaxKey[row]) - DELTA;
        if (v1[s] >= thr) {
            int pos = atomicAdd(&cnt[row], 1);
            if (pos < CAP) list[row][pos] = k1[s];
        }
        if (v2[s] >= thr) {
            int pos = atomicAdd(&cnt[row], 1);
            if (pos < CAP) list[row][pos] = FLAGBIT | (wid * 16 + lo);
        }
    }
    __syncthreads();

    if (tid < BM) {
        int c = cnt[tid];
        cand_cnt[m0 + tid] = (unsigned char)(c > CAP ? 255 : c);
        int n = c < CAP ? c : CAP;
        for (int j = 0; j < n; ++j) cand_k[(size_t)(m0 + tid) * CAP + j] = list[tid][j];
    }
}

// ---------------- kernel 3: rescore (incl. stream rescans) + outputs ----------------
__global__ __launch_bounds__(256, 1) void k_final(
    const float* __restrict__ z,
    const float* __restrict__ E,
    const float* __restrict__ En,
    const unsigned char* __restrict__ cand_cnt,
    const int* __restrict__ cand_k,
    float* __restrict__ out,
    float* __restrict__ rowloss) {

    __shared__ float zl[4][256];
    int wid  = threadIdx.x >> 6;
    int lane = threadIdx.x & 63;
    int m    = blockIdx.x * 4 + wid;

    const float* zr = z + (size_t)m * DDIM;
    const float4 zz = *(const float4*)&zr[lane * 4];
    *(float4*)&zl[wid][lane * 4] = zz;          // full z row for stream rescans
    asm volatile("s_waitcnt lgkmcnt(0)" ::: "memory");

    float bv = -FLT_MAX;
    int   bk = 0x7fffffff;

    // rescan one column-stream (codes k ≡ cb mod 64), 2 codes/lane, exact fp32
    auto rescan = [&](int cb) {
#pragma unroll
        for (int j = 0; j < 2; ++j) {
            int k = cb + (lane * 2 + j) * 64;
            const float4* er = (const float4*)&En[(size_t)k * DDIM];
            float s0 = 0.f, s1 = 0.f, s2 = 0.f, s3 = 0.f;
#pragma unroll 16
            for (int d4 = 0; d4 < 64; ++d4) {
                float4 e  = er[d4];
                float4 zd = *(const float4*)&zl[wid][d4 * 4];
                s0 += zd.x * e.x; s1 += zd.y * e.y;
                s2 += zd.z * e.z; s3 += zd.w * e.w;
            }
            float s = (s0 + s1) + (s2 + s3);
            if (s > bv || (s == bv && k < bk)) { bv = s; bk = k; }
        }
    };

    int c = cand_cnt[m];
    if (c != 255) {
        for (int j = 0; j < c; ++j) {
            int e = cand_k[(size_t)m * CAP + j];
            if (e < FLAGBIT) {
                const float4 ee = *(const float4*)&En[(size_t)e * DDIM + lane * 4];
                float s = zz.x * ee.x + zz.y * ee.y + zz.z * ee.z + zz.w * ee.w;
#pragma unroll
                for (int off = 1; off < 64; off <<= 1) s += __shfl_xor(s, off);
                if (s > bv || (s == bv && e < bk)) { bv = s; bk = e; }
            } else {
                rescan(e & 63);
            }
        }
    } else {
        for (int cb = 0; cb < 64; ++cb) rescan(cb);   // overflow: full exact scan
    }
    // final argmax reduce across lanes (value, min-k tie)
#pragma unroll
    for (int off = 1; off < 64; off <<= 1) {
        float ov = __shfl_xor(bv, off);
        int   ok = __shfl_xor(bk, off);
        if (ov > bv || (ov == bv && ok < bk)) { bv = ov; bk = ok; }
    }
    const int idx = bk;

    // ---- gather + straight-through + per-row loss ----
    const float* er = E + (size_t)idx * DDIM;
    float zv[4], ev[4];
    float sz = 0.f, se = 0.f;
#pragma unroll
    for (int p = 0; p < 4; ++p) {
        zv[p] = zr[lane + 64 * p]; sz += zv[p] * zv[p];
        ev[p] = er[lane + 64 * p]; se += ev[p] * ev[p];
    }
#pragma unroll
    for (int off = 32; off >= 1; off >>= 1) {
        sz += __shfl_xor(sz, off);
        se += __shfl_xor(se, off);
    }
    float nz = fmaxf(sqrtf(sz), 1e-8f);
    float ne = fmaxf(sqrtf(se), 1e-8f);

    float rs = 0.f;
    float* zq = out + 1 + (size_t)m * DDIM;
#pragma unroll
    for (int p = 0; p < 4; ++p) {
        float zn = zv[p] / nz;
        float en = ev[p] / ne;
        float d  = en - zn;
        rs += d * d;
        zq[lane + 64 * p] = zv[p] + (ev[p] - zv[p]);
    }
#pragma unroll
    for (int off = 32; off >= 1; off >>= 1) rs += __shfl_xor(rs, off);

    if (lane == 0) {
        rowloss[m] = rs;
        out[1 + (size_t)M_ROWS * DDIM + m] = (float)idx;
    }
}

// ---------------- kernel 4: deterministic loss reduction ----------------
__global__ __launch_bounds__(256) void k_loss(const float* __restrict__ rowloss,
                                              float* __restrict__ out) {
    __shared__ double sm[256];
    double s = 0.0;
    for (int i = threadIdx.x; i < M_ROWS; i += 256) s += (double)rowloss[i];
    sm[threadIdx.x] = s;
    __syncthreads();
    for (int st = 128; st > 0; st >>= 1) {
        if (threadIdx.x < st) sm[threadIdx.x] += sm[threadIdx.x + st];
        __syncthreads();
    }
    if (threadIdx.x == 0) {
        float c = (float)(sm[0] / (double)((size_t)M_ROWS * DDIM));
        out[0] = c + 0.05f * c;
    }
}

extern "C" void kernel_launch(void* const* d_in, const int* in_sizes, int n_in,
                              void* d_out, int out_size, void* d_ws, size_t ws_size,
                              hipStream_t stream) {
    const float* z = (const float*)d_in[0];
    const float* E = (const float*)d_in[1];
    float* out = (float*)d_out;

    char* ws = (char*)d_ws;
    size_t off = 0;
    float*          En       = (float*)(ws + off);          off += (size_t)K_CODES * DDIM * 4;  // 8 MB
    unsigned short* En_b     = (unsigned short*)(ws + off); off += (size_t)K_CODES * DDIM * 2;  // 4 MB
    int*            cand_k   = (int*)(ws + off);            off += (size_t)M_ROWS * CAP * 4;    // 2 MB
    unsigned char*  cand_cnt = (unsigned char*)(ws + off);  off += (size_t)M_ROWS;              // 32 KB
    float*          rowloss  = (float*)(ws + off);

    k_norm_E<<<K_CODES / 4, 256, 0, stream>>>(E, En, En_b);
    k_cand<<<M_ROWS / BM, 256, 0, stream>>>(z, En_b, cand_cnt, cand_k);
    k_final<<<M_ROWS / 4, 256, 0, stream>>>(z, E, En, cand_cnt, cand_k, out, rowloss);
    k_loss<<<1, 256, 0, stream>>>(rowloss, out);
}

// Round 15
// 325.234 us; speedup vs baseline: 1.7709x; 1.3129x over previous
//
#include <hip/hip_runtime.h>
#include <float.h>
#include <math.h>
#include <stdint.h>

#define M_ROWS 32768
#define K_CODES 8192
#define DDIM 256
#define BM 64
#define BN 64
#define NTILES (K_CODES / BN)   // 128
#define DELTA 0.009f
#define CAP 16
#define FLAGBIT 0x10000

typedef __attribute__((ext_vector_type(8))) short short8;
typedef __attribute__((ext_vector_type(4))) float f32x4;

__device__ inline unsigned short f2bf(float f) {
    unsigned u = __float_as_uint(f);
    return (unsigned short)((u + 0x7fffu + ((u >> 16) & 1u)) >> 16);
}
__device__ inline unsigned fkey(float f) {
    unsigned u = __float_as_uint(f);
    return u ^ ((unsigned)((int)u >> 31) | 0x80000000u);
}
__device__ inline float fkey_inv(unsigned k) {
    unsigned u = (k & 0x80000000u) ? (k ^ 0x80000000u) : ~k;
    return __uint_as_float(u);
}

#define GLOAD16(gsrc, ldst)                                                     \
    __builtin_amdgcn_global_load_lds(                                           \
        (const __attribute__((address_space(1))) void*)(gsrc),                  \
        (__attribute__((address_space(3))) void*)(ldst), 16, 0, 0)

// ---------------- kernel 1: normalize E -> En (fp32) + En_b (bf16) ----------------
__global__ __launch_bounds__(256) void k_norm_E(const float* __restrict__ E,
                                                float* __restrict__ En,
                                                unsigned short* __restrict__ En_b) {
    int wid  = threadIdx.x >> 6;
    int lane = threadIdx.x & 63;
    int row  = blockIdx.x * 4 + wid;
    const float* e = E + (size_t)row * DDIM;
    float v[4];
    float ssq = 0.f;
#pragma unroll
    for (int p = 0; p < 4; ++p) { v[p] = e[lane + 64 * p]; ssq += v[p] * v[p]; }
#pragma unroll
    for (int off = 32; off >= 1; off >>= 1) ssq += __shfl_xor(ssq, off);
    float inv = 1.f / fmaxf(sqrtf(ssq), 1e-8f);
    float* o = En + (size_t)row * DDIM;
    unsigned short* ob = En_b + (size_t)row * DDIM;
#pragma unroll
    for (int p = 0; p < 4; ++p) {
        float nv = v[p] * inv;
        o[lane + 64 * p]  = nv;
        ob[lane + 64 * p] = f2bf(nv);
    }
}

// ---------------- kernel 2: single-pass top-2 filter, barrier-free wave pipeline --
// 256 thr = 4 waves; BM=64 rows all in registers per wave (af[4][8] = 128 VGPR,
// 4-MFMA reuse per ds_read); wave wid owns cols wid*16+lo of each BN=64 tile.
// Each wave stages its OWN 8KB col-slice into a private 2x8KB LDS double buffer
// (global_load_lds depth-2, per-wave counted vmcnt(8)) -- ZERO block barriers in
// the 128-tile loop (R14's per-tile __syncthreads drained the in-flight stage,
// ~2500 cyc/phase of exposed latency). (256,1): free VGPR alloc (R12-R14), but
// 1 block/CU residency -- latency hiding comes from per-wave ILP + depth-2.
// Streaming per-(slot,lane) top-2 (v1/k1/v2); end: exact bf16 rowmax -> thr;
// emit k1 if v1>=thr; emit FLAG(col) if v2>=thr (k_final rescans that stream).
__global__ __launch_bounds__(256, 1) void k_cand(
    const float* __restrict__ z,
    const unsigned short* __restrict__ En_b,
    unsigned char* __restrict__ cand_cnt,
    int* __restrict__ cand_k) {

    __shared__ __attribute__((aligned(16))) char Bw[4][2][8192];  // 64 KB
    __shared__ unsigned rowmaxKey[BM];
    __shared__ int cnt[BM];
    __shared__ int list[BM][CAP];                                  // 4 KB

    const int tid  = threadIdx.x;
    const int lane = tid & 63;
    const int wid  = tid >> 6;      // col-group 0..3
    const int lo   = lane & 15;
    const int hi   = lane >> 4;
    const int m0   = blockIdx.x * BM;

    if (tid < BM) { cnt[tid] = 0; rowmaxKey[tid] = 0u; }

    const char* eb = (const char*)En_b;
    char* b0 = &Bw[wid][0][0];
    char* b1 = &Bw[wid][1][0];

    // stage this wave's 8KB slice (16 codes) of tile ktile: 8 x global_load_lds
    auto stage = [&](int ktile, char* bufp) {
#pragma unroll
        for (int i = 0; i < 8; ++i) {
            int G   = i * 64 + lane;            // granule 0..511 in slice
            int row = G >> 5;                   // 0..15 (code within slice)
            int g   = (G & 31) ^ (row & 7);     // pre-swizzled 16B granule
            GLOAD16(eb + (size_t)(ktile * BN + wid * 16 + row) * 512 + g * 16,
                    bufp + i * 1024);
        }
    };

    stage(0, b0);
    stage(1, b1);

    // ---- A fragments: z fp32 -> normalize in-register -> bf16 ----
    short8 af[4][8];
#pragma unroll
    for (int mi = 0; mi < 4; ++mi) {
        const float* zr = z + (size_t)(m0 + mi * 16 + lo) * DDIM;
        float4 v[16];
        float ssq = 0.f;
#pragma unroll
        for (int ks = 0; ks < 8; ++ks) {
            int e0 = (ks * 4 + hi) * 8;
            v[2 * ks]     = *(const float4*)&zr[e0];
            v[2 * ks + 1] = *(const float4*)&zr[e0 + 4];
            float4 a = v[2 * ks], b = v[2 * ks + 1];
            ssq += a.x * a.x + a.y * a.y + a.z * a.z + a.w * a.w;
            ssq += b.x * b.x + b.y * b.y + b.z * b.z + b.w * b.w;
        }
        ssq += __shfl_xor(ssq, 16);
        ssq += __shfl_xor(ssq, 32);
        float inv = 1.f / fmaxf(sqrtf(ssq), 1e-8f);
#pragma unroll
        for (int ks = 0; ks < 8; ++ks) {
            float4 a = v[2 * ks], b = v[2 * ks + 1];
            short8 s8;
            s8[0] = (short)f2bf(a.x * inv); s8[1] = (short)f2bf(a.y * inv);
            s8[2] = (short)f2bf(a.z * inv); s8[3] = (short)f2bf(a.w * inv);
            s8[4] = (short)f2bf(b.x * inv); s8[5] = (short)f2bf(b.y * inv);
            s8[6] = (short)f2bf(b.z * inv); s8[7] = (short)f2bf(b.w * inv);
            af[mi][ks] = s8;
        }
    }

    // per-slot stream state (slot s = mi*4+r; row = mi*16 + hi*4 + r)
    float v1[16], v2[16];
    int   k1[16];
#pragma unroll
    for (int s = 0; s < 16; ++s) { v1[s] = -FLT_MAX; v2[s] = -FLT_MAX; k1[s] = 0; }

    __syncthreads();   // cnt/rowmaxKey init visible (one-time; also drains prologue)

    const int bswz = lo & 7;

    for (int t = 0; t < NTILES; ++t) {
        if (t < NTILES - 1) asm volatile("s_waitcnt vmcnt(8)" ::: "memory");
        else                asm volatile("s_waitcnt vmcnt(0)" ::: "memory");
        __builtin_amdgcn_sched_barrier(0);

        const unsigned short* Bc = (const unsigned short*)((t & 1) ? b1 : b0);
        f32x4 acc[4];
#pragma unroll
        for (int mi = 0; mi < 4; ++mi) acc[mi] = (f32x4){0.f, 0.f, 0.f, 0.f};
#pragma unroll
        for (int ks = 0; ks < 8; ++ks) {
            short8 bf = *(const short8*)&Bc[lo * 256 + (((ks * 4 + hi) ^ bswz)) * 8];
#pragma unroll
            for (int mi = 0; mi < 4; ++mi)
                acc[mi] = __builtin_amdgcn_mfma_f32_16x16x32_bf16(af[mi][ks], bf, acc[mi], 0, 0, 0);
        }

        const int kv = t * BN + wid * 16 + lo;
#pragma unroll
        for (int mi = 0; mi < 4; ++mi)
#pragma unroll
            for (int r = 0; r < 4; ++r) {
                int s = mi * 4 + r;
                float v = acc[mi][r];
                v2[s] = fmaxf(v2[s], fminf(v1[s], v));    // streaming 2nd max
                k1[s] = (v > v1[s]) ? kv : k1[s];
                v1[s] = fmaxf(v1[s], v);
            }

        if (t + 2 < NTILES) {
            // ds_reads of this tile complete before overwriting the buffer
            asm volatile("s_waitcnt lgkmcnt(0)" ::: "memory");
            __builtin_amdgcn_sched_barrier(0);
            stage(t + 2, (t & 1) ? b1 : b0);
        }
    }

    // ---- exact bf16 row max: reduce v1 over 16 lo-lanes, cross-wave via LDS ----
#pragma unroll
    for (int s = 0; s < 16; ++s) {
        float w = v1[s];
        w = fmaxf(w, __shfl_xor(w, 1));
        w = fmaxf(w, __shfl_xor(w, 2));
        w = fmaxf(w, __shfl_xor(w, 4));
        w = fmaxf(w, __shfl_xor(w, 8));
        if (lo == 0) {
            int row = (s >> 2) * 16 + hi * 4 + (s & 3);
            atomicMax(&rowmaxKey[row], fkey(w));
        }
    }
    __syncthreads();

    // ---- emit candidates + flag entries ----
#pragma unroll
    for (int s = 0; s < 16; ++s) {
        int row = (s >> 2) * 16 + hi * 4 + (s & 3);
        float thr = fkey_inv(rowmaxKey[row]) - DELTA;
        if (v1[s] >= thr) {
            int pos = atomicAdd(&cnt[row], 1);
            if (pos < CAP) list[row][pos] = k1[s];
        }
        if (v2[s] >= thr) {
            int pos = atomicAdd(&cnt[row], 1);
            if (pos < CAP) list[row][pos] = FLAGBIT | (wid * 16 + lo);
        }
    }
    __syncthreads();

    if (tid < BM) {
        int c = cnt[tid];
        cand_cnt[m0 + tid] = (unsigned char)(c > CAP ? 255 : c);
        int n = c < CAP ? c : CAP;
        for (int j = 0; j < n; ++j) cand_k[(size_t)(m0 + tid) * CAP + j] = list[tid][j];
    }
}

// ---------------- kernel 3: rescore (incl. stream rescans) + outputs ----------------
__global__ __launch_bounds__(256, 1) void k_final(
    const float* __restrict__ z,
    const float* __restrict__ E,
    const float* __restrict__ En,
    const unsigned char* __restrict__ cand_cnt,
    const int* __restrict__ cand_k,
    float* __restrict__ out,
    float* __restrict__ rowloss) {

    __shared__ float zl[4][256];
    int wid  = threadIdx.x >> 6;
    int lane = threadIdx.x & 63;
    int m    = blockIdx.x * 4 + wid;

    const float* zr = z + (size_t)m * DDIM;
    const float4 zz = *(const float4*)&zr[lane * 4];
    *(float4*)&zl[wid][lane * 4] = zz;          // full z row for stream rescans
    asm volatile("s_waitcnt lgkmcnt(0)" ::: "memory");

    float bv = -FLT_MAX;
    int   bk = 0x7fffffff;

    // rescan one column-stream (codes k ≡ cb mod 64), 2 codes/lane, exact fp32
    auto rescan = [&](int cb) {
#pragma unroll
        for (int j = 0; j < 2; ++j) {
            int k = cb + (lane * 2 + j) * 64;
            const float4* er = (const float4*)&En[(size_t)k * DDIM];
            float s0 = 0.f, s1 = 0.f, s2 = 0.f, s3 = 0.f;
#pragma unroll 16
            for (int d4 = 0; d4 < 64; ++d4) {
                float4 e  = er[d4];
                float4 zd = *(const float4*)&zl[wid][d4 * 4];
                s0 += zd.x * e.x; s1 += zd.y * e.y;
                s2 += zd.z * e.z; s3 += zd.w * e.w;
            }
            float s = (s0 + s1) + (s2 + s3);
            if (s > bv || (s == bv && k < bk)) { bv = s; bk = k; }
        }
    };

    int c = cand_cnt[m];
    if (c != 255) {
        for (int j = 0; j < c; ++j) {
            int e = cand_k[(size_t)m * CAP + j];
            if (e < FLAGBIT) {
                const float4 ee = *(const float4*)&En[(size_t)e * DDIM + lane * 4];
                float s = zz.x * ee.x + zz.y * ee.y + zz.z * ee.z + zz.w * ee.w;
#pragma unroll
                for (int off = 1; off < 64; off <<= 1) s += __shfl_xor(s, off);
                if (s > bv || (s == bv && e < bk)) { bv = s; bk = e; }
            } else {
                rescan(e & 63);
            }
        }
    } else {
        for (int cb = 0; cb < 64; ++cb) rescan(cb);   // overflow: full exact scan
    }
    // final argmax reduce across lanes (value, min-k tie)
#pragma unroll
    for (int off = 1; off < 64; off <<= 1) {
        float ov = __shfl_xor(bv, off);
        int   ok = __shfl_xor(bk, off);
        if (ov > bv || (ov == bv && ok < bk)) { bv = ov; bk = ok; }
    }
    const int idx = bk;

    // ---- gather + straight-through + per-row loss ----
    const float* er = E + (size_t)idx * DDIM;
    float zv[4], ev[4];
    float sz = 0.f, se = 0.f;
#pragma unroll
    for (int p = 0; p < 4; ++p) {
        zv[p] = zr[lane + 64 * p]; sz += zv[p] * zv[p];
        ev[p] = er[lane + 64 * p]; se += ev[p] * ev[p];
    }
#pragma unroll
    for (int off = 32; off >= 1; off >>= 1) {
        sz += __shfl_xor(sz, off);
        se += __shfl_xor(se, off);
    }
    float nz = fmaxf(sqrtf(sz), 1e-8f);
    float ne = fmaxf(sqrtf(se), 1e-8f);

    float rs = 0.f;
    float* zq = out + 1 + (size_t)m * DDIM;
#pragma unroll
    for (int p = 0; p < 4; ++p) {
        float zn = zv[p] / nz;
        float en = ev[p] / ne;
        float d  = en - zn;
        rs += d * d;
        zq[lane + 64 * p] = zv[p] + (ev[p] - zv[p]);
    }
#pragma unroll
    for (int off = 32; off >= 1; off >>= 1) rs += __shfl_xor(rs, off);

    if (lane == 0) {
        rowloss[m] = rs;
        out[1 + (size_t)M_ROWS * DDIM + m] = (float)idx;
    }
}

// ---------------- kernel 4: deterministic loss reduction ----------------
__global__ __launch_bounds__(256) void k_loss(const float* __restrict__ rowloss,
                                              float* __restrict__ out) {
    __shared__ double sm[256];
    double s = 0.0;
    for (int i = threadIdx.x; i < M_ROWS; i += 256) s += (double)rowloss[i];
    sm[threadIdx.x] = s;
    __syncthreads();
    for (int st = 128; st > 0; st >>= 1) {
        if (threadIdx.x < st) sm[threadIdx.x] += sm[threadIdx.x + st];
        __syncthreads();
    }
    if (threadIdx.x == 0) {
        float c = (float)(sm[0] / (double)((size_t)M_ROWS * DDIM));
        out[0] = c + 0.05f * c;
    }
}

extern "C" void kernel_launch(void* const* d_in, const int* in_sizes, int n_in,
                              void* d_out, int out_size, void* d_ws, size_t ws_size,
                              hipStream_t stream) {
    const float* z = (const float*)d_in[0];
    const float* E = (const float*)d_in[1];
    float* out = (float*)d_out;

    char* ws = (char*)d_ws;
    size_t off = 0;
    float*          En       = (float*)(ws + off);          off += (size_t)K_CODES * DDIM * 4;  // 8 MB
    unsigned short* En_b     = (unsigned short*)(ws + off); off += (size_t)K_CODES * DDIM * 2;  // 4 MB
    int*            cand_k   = (int*)(ws + off);            off += (size_t)M_ROWS * CAP * 4;    // 2 MB
    unsigned char*  cand_cnt = (unsigned char*)(ws + off);  off += (size_t)M_ROWS;              // 32 KB
    float*          rowloss  = (float*)(ws + off);

    k_norm_E<<<K_CODES / 4, 256, 0, stream>>>(E, En, En_b);
    k_cand<<<M_ROWS / BM, 256, 0, stream>>>(z, En_b, cand_cnt, cand_k);
    k_final<<<M_ROWS / 4, 256, 0, stream>>>(z, E, En, cand_cnt, cand_k, out, rowloss);
    k_loss<<<1, 256, 0, stream>>>(rowloss, out);
}

// Round 16
// 319.449 us; speedup vs baseline: 1.8030x; 1.0181x over previous
//
#include <hip/hip_runtime.h>
#include <float.h>
#include <math.h>
#include <stdint.h>

#define M_ROWS 32768
#define K_CODES 8192
#define DDIM 256
#define BM 64
#define BN 64
#define NTILES (K_CODES / BN)   // 128
#define DELTA 0.009f
#define CAP 16
#define FLAGBIT 0x10000

typedef __attribute__((ext_vector_type(8))) short short8;
typedef __attribute__((ext_vector_type(4))) float f32x4;

__device__ inline unsigned short f2bf(float f) {
    unsigned u = __float_as_uint(f);
    return (unsigned short)((u + 0x7fffu + ((u >> 16) & 1u)) >> 16);
}
__device__ inline unsigned fkey(float f) {
    unsigned u = __float_as_uint(f);
    return u ^ ((unsigned)((int)u >> 31) | 0x80000000u);
}
__device__ inline float fkey_inv(unsigned k) {
    unsigned u = (k & 0x80000000u) ? (k ^ 0x80000000u) : ~k;
    return __uint_as_float(u);
}

#define GLOAD16(gsrc, ldst)                                                     \
    __builtin_amdgcn_global_load_lds(                                           \
        (const __attribute__((address_space(1))) void*)(gsrc),                  \
        (__attribute__((address_space(3))) void*)(ldst), 16, 0, 0)

// ---------------- kernel 1: normalize E -> En (fp32) + En_b (bf16) ----------------
__global__ __launch_bounds__(256) void k_norm_E(const float* __restrict__ E,
                                                float* __restrict__ En,
                                                unsigned short* __restrict__ En_b) {
    int wid  = threadIdx.x >> 6;
    int lane = threadIdx.x & 63;
    int row  = blockIdx.x * 4 + wid;
    const float* e = E + (size_t)row * DDIM;
    float v[4];
    float ssq = 0.f;
#pragma unroll
    for (int p = 0; p < 4; ++p) { v[p] = e[lane + 64 * p]; ssq += v[p] * v[p]; }
#pragma unroll
    for (int off = 32; off >= 1; off >>= 1) ssq += __shfl_xor(ssq, off);
    float inv = 1.f / fmaxf(sqrtf(ssq), 1e-8f);
    float* o = En + (size_t)row * DDIM;
    unsigned short* ob = En_b + (size_t)row * DDIM;
#pragma unroll
    for (int p = 0; p < 4; ++p) {
        float nv = v[p] * inv;
        o[lane + 64 * p]  = nv;
        ob[lane + 64 * p] = f2bf(nv);
    }
}

// ---------------- kernel 2: single-pass top-2 filter, barrier-free wave pipeline --
// Structure = R15 (proven: 245us). ONE change: occupancy metadata.
// R7-R15 evidence: __launch_bounds__(B,N) sets waves-per-EU min=max=N ->
// (256,1) freed the register file (160 VGPR, no spill) but CLAMPED runtime to
// 1 wave/SIMD, so MFMA (24%) and VALU (43%) serialize on the same wave.
// amdgpu_waves_per_eu(1,2): min=1 keeps the 256-reg budget, max=2 lets the HW
// co-schedule the 2nd block/CU (160 VGPR and 2x70KB LDS both fit) -> two
// independent de-phased blocks overlap MFMA/VALU/LDS pipes (m114 mechanism).
__global__ __attribute__((amdgpu_flat_work_group_size(256, 256),
                          amdgpu_waves_per_eu(1, 2)))
void k_cand(
    const float* __restrict__ z,
    const unsigned short* __restrict__ En_b,
    unsigned char* __restrict__ cand_cnt,
    int* __restrict__ cand_k) {

    __shared__ __attribute__((aligned(16))) char Bw[4][2][8192];  // 64 KB
    __shared__ unsigned rowmaxKey[BM];
    __shared__ int cnt[BM];
    __shared__ int list[BM][CAP];                                  // 4 KB

    const int tid  = threadIdx.x;
    const int lane = tid & 63;
    const int wid  = tid >> 6;      // col-group 0..3
    const int lo   = lane & 15;
    const int hi   = lane >> 4;
    const int m0   = blockIdx.x * BM;

    if (tid < BM) { cnt[tid] = 0; rowmaxKey[tid] = 0u; }

    const char* eb = (const char*)En_b;
    char* b0 = &Bw[wid][0][0];
    char* b1 = &Bw[wid][1][0];

    // precomputed per-lane stage source offsets (VALU trim: addr = tilebase+sofs[i])
    int sofs[8];
#pragma unroll
    for (int i = 0; i < 8; ++i) {
        int G   = i * 64 + lane;            // granule 0..511 in slice
        int row = G >> 5;                   // 0..15 (code within slice)
        int g   = (G & 31) ^ (row & 7);     // pre-swizzled 16B granule
        sofs[i] = (wid * 16 + row) * 512 + g * 16;
    }

    auto stage = [&](int ktile, char* bufp) {
        const char* tb = eb + (size_t)ktile * (BN * 512);
#pragma unroll
        for (int i = 0; i < 8; ++i)
            GLOAD16(tb + sofs[i], bufp + i * 1024);
    };

    stage(0, b0);
    stage(1, b1);

    // ---- A fragments: z fp32 -> normalize in-register -> bf16 ----
    short8 af[4][8];
#pragma unroll
    for (int mi = 0; mi < 4; ++mi) {
        const float* zr = z + (size_t)(m0 + mi * 16 + lo) * DDIM;
        float4 v[16];
        float ssq = 0.f;
#pragma unroll
        for (int ks = 0; ks < 8; ++ks) {
            int e0 = (ks * 4 + hi) * 8;
            v[2 * ks]     = *(const float4*)&zr[e0];
            v[2 * ks + 1] = *(const float4*)&zr[e0 + 4];
            float4 a = v[2 * ks], b = v[2 * ks + 1];
            ssq += a.x * a.x + a.y * a.y + a.z * a.z + a.w * a.w;
            ssq += b.x * b.x + b.y * b.y + b.z * b.z + b.w * b.w;
        }
        ssq += __shfl_xor(ssq, 16);
        ssq += __shfl_xor(ssq, 32);
        float inv = 1.f / fmaxf(sqrtf(ssq), 1e-8f);
#pragma unroll
        for (int ks = 0; ks < 8; ++ks) {
            float4 a = v[2 * ks], b = v[2 * ks + 1];
            short8 s8;
            s8[0] = (short)f2bf(a.x * inv); s8[1] = (short)f2bf(a.y * inv);
            s8[2] = (short)f2bf(a.z * inv); s8[3] = (short)f2bf(a.w * inv);
            s8[4] = (short)f2bf(b.x * inv); s8[5] = (short)f2bf(b.y * inv);
            s8[6] = (short)f2bf(b.z * inv); s8[7] = (short)f2bf(b.w * inv);
            af[mi][ks] = s8;
        }
    }

    // per-slot stream state (slot s = mi*4+r; row = mi*16 + hi*4 + r)
    float v1[16], v2[16];
    int   k1[16];
#pragma unroll
    for (int s = 0; s < 16; ++s) { v1[s] = -FLT_MAX; v2[s] = -FLT_MAX; k1[s] = 0; }

    __syncthreads();   // init visible (one-time; also drains prologue staging)

    const int bswz = lo & 7;

    for (int t = 0; t < NTILES; ++t) {
        if (t < NTILES - 1) asm volatile("s_waitcnt vmcnt(8)" ::: "memory");
        else                asm volatile("s_waitcnt vmcnt(0)" ::: "memory");
        __builtin_amdgcn_sched_barrier(0);

        const unsigned short* Bc = (const unsigned short*)((t & 1) ? b1 : b0);
        f32x4 acc[4];
#pragma unroll
        for (int mi = 0; mi < 4; ++mi) acc[mi] = (f32x4){0.f, 0.f, 0.f, 0.f};
#pragma unroll
        for (int ks = 0; ks < 8; ++ks) {
            short8 bf = *(const short8*)&Bc[lo * 256 + (((ks * 4 + hi) ^ bswz)) * 8];
#pragma unroll
            for (int mi = 0; mi < 4; ++mi)
                acc[mi] = __builtin_amdgcn_mfma_f32_16x16x32_bf16(af[mi][ks], bf, acc[mi], 0, 0, 0);
        }

        const int kv = t * BN + wid * 16 + lo;
#pragma unroll
        for (int mi = 0; mi < 4; ++mi)
#pragma unroll
            for (int r = 0; r < 4; ++r) {
                int s = mi * 4 + r;
                float v = acc[mi][r];
                v2[s] = fmaxf(v2[s], fminf(v1[s], v));    // streaming 2nd max
                k1[s] = (v > v1[s]) ? kv : k1[s];
                v1[s] = fmaxf(v1[s], v);
            }

        if (t + 2 < NTILES) {
            // ds_reads of this tile complete before overwriting the buffer
            asm volatile("s_waitcnt lgkmcnt(0)" ::: "memory");
            __builtin_amdgcn_sched_barrier(0);
            stage(t + 2, (t & 1) ? b1 : b0);
        }
    }

    // ---- exact bf16 row max: reduce v1 over 16 lo-lanes, cross-wave via LDS ----
#pragma unroll
    for (int s = 0; s < 16; ++s) {
        float w = v1[s];
        w = fmaxf(w, __shfl_xor(w, 1));
        w = fmaxf(w, __shfl_xor(w, 2));
        w = fmaxf(w, __shfl_xor(w, 4));
        w = fmaxf(w, __shfl_xor(w, 8));
        if (lo == 0) {
            int row = (s >> 2) * 16 + hi * 4 + (s & 3);
            atomicMax(&rowmaxKey[row], fkey(w));
        }
    }
    __syncthreads();

    // ---- emit candidates + flag entries ----
#pragma unroll
    for (int s = 0; s < 16; ++s) {
        int row = (s >> 2) * 16 + hi * 4 + (s & 3);
        float thr = fkey_inv(rowmaxKey[row]) - DELTA;
        if (v1[s] >= thr) {
            int pos = atomicAdd(&cnt[row], 1);
            if (pos < CAP) list[row][pos] = k1[s];
        }
        if (v2[s] >= thr) {
            int pos = atomicAdd(&cnt[row], 1);
            if (pos < CAP) list[row][pos] = FLAGBIT | (wid * 16 + lo);
        }
    }
    __syncthreads();

    if (tid < BM) {
        int c = cnt[tid];
        cand_cnt[m0 + tid] = (unsigned char)(c > CAP ? 255 : c);
        int n = c < CAP ? c : CAP;
        for (int j = 0; j < n; ++j) cand_k[(size_t)(m0 + tid) * CAP + j] = list[tid][j];
    }
}

// ---------------- kernel 3: rescore (incl. stream rescans) + outputs ----------------
__global__ __launch_bounds__(256) void k_final(
    const float* __restrict__ z,
    const float* __restrict__ E,
    const float* __restrict__ En,
    const unsigned char* __restrict__ cand_cnt,
    const int* __restrict__ cand_k,
    float* __restrict__ out,
    float* __restrict__ rowloss) {

    __shared__ float zl[4][256];
    int wid  = threadIdx.x >> 6;
    int lane = threadIdx.x & 63;
    int m    = blockIdx.x * 4 + wid;

    const float* zr = z + (size_t)m * DDIM;
    const float4 zz = *(const float4*)&zr[lane * 4];
    *(float4*)&zl[wid][lane * 4] = zz;          // full z row for stream rescans
    asm volatile("s_waitcnt lgkmcnt(0)" ::: "memory");

    float bv = -FLT_MAX;
    int   bk = 0x7fffffff;

    // rescan one column-stream (codes k ≡ cb mod 64), 2 codes/lane, exact fp32
    auto rescan = [&](int cb) {
#pragma unroll
        for (int j = 0; j < 2; ++j) {
            int k = cb + (lane * 2 + j) * 64;
            const float4* er = (const float4*)&En[(size_t)k * DDIM];
            float s0 = 0.f, s1 = 0.f, s2 = 0.f, s3 = 0.f;
#pragma unroll 16
            for (int d4 = 0; d4 < 64; ++d4) {
                float4 e  = er[d4];
                float4 zd = *(const float4*)&zl[wid][d4 * 4];
                s0 += zd.x * e.x; s1 += zd.y * e.y;
                s2 += zd.z * e.z; s3 += zd.w * e.w;
            }
            float s = (s0 + s1) + (s2 + s3);
            if (s > bv || (s == bv && k < bk)) { bv = s; bk = k; }
        }
    };

    int c = cand_cnt[m];
    if (c != 255) {
        for (int j = 0; j < c; ++j) {
            int e = cand_k[(size_t)m * CAP + j];
            if (e < FLAGBIT) {
                const float4 ee = *(const float4*)&En[(size_t)e * DDIM + lane * 4];
                float s = zz.x * ee.x + zz.y * ee.y + zz.z * ee.z + zz.w * ee.w;
#pragma unroll
                for (int off = 1; off < 64; off <<= 1) s += __shfl_xor(s, off);
                if (s > bv || (s == bv && e < bk)) { bv = s; bk = e; }
            } else {
                rescan(e & 63);
            }
        }
    } else {
        for (int cb = 0; cb < 64; ++cb) rescan(cb);   // overflow: full exact scan
    }
    // final argmax reduce across lanes (value, min-k tie)
#pragma unroll
    for (int off = 1; off < 64; off <<= 1) {
        float ov = __shfl_xor(bv, off);
        int   ok = __shfl_xor(bk, off);
        if (ov > bv || (ov == bv && ok < bk)) { bv = ov; bk = ok; }
    }
    const int idx = bk;

    // ---- gather + straight-through + per-row loss ----
    const float* er = E + (size_t)idx * DDIM;
    float zv[4], ev[4];
    float sz = 0.f, se = 0.f;
#pragma unroll
    for (int p = 0; p < 4; ++p) {
        zv[p] = zr[lane + 64 * p]; sz += zv[p] * zv[p];
        ev[p] = er[lane + 64 * p]; se += ev[p] * ev[p];
    }
#pragma unroll
    for (int off = 32; off >= 1; off >>= 1) {
        sz += __shfl_xor(sz, off);
        se += __shfl_xor(se, off);
    }
    float nz = fmaxf(sqrtf(sz), 1e-8f);
    float ne = fmaxf(sqrtf(se), 1e-8f);

    float rs = 0.f;
    float* zq = out + 1 + (size_t)m * DDIM;
#pragma unroll
    for (int p = 0; p < 4; ++p) {
        float zn = zv[p] / nz;
        float en = ev[p] / ne;
        float d  = en - zn;
        rs += d * d;
        zq[lane + 64 * p] = zv[p] + (ev[p] - zv[p]);
    }
#pragma unroll
    for (int off = 32; off >= 1; off >>= 1) rs += __shfl_xor(rs, off);

    if (lane == 0) {
        rowloss[m] = rs;
        out[1 + (size_t)M_ROWS * DDIM + m] = (float)idx;
    }
}

// ---------------- kernel 4: deterministic loss reduction ----------------
__global__ __launch_bounds__(256) void k_loss(const float* __restrict__ rowloss,
                                              float* __restrict__ out) {
    __shared__ double sm[256];
    double s = 0.0;
    for (int i = threadIdx.x; i < M_ROWS; i += 256) s += (double)rowloss[i];
    sm[threadIdx.x] = s;
    __syncthreads();
    for (int st = 128; st > 0; st >>= 1) {
        if (threadIdx.x < st) sm[threadIdx.x] += sm[threadIdx.x + st];
        __syncthreads();
    }
    if (threadIdx.x == 0) {
        float c = (float)(sm[0] / (double)((size_t)M_ROWS * DDIM));
        out[0] = c + 0.05f * c;
    }
}

extern "C" void kernel_launch(void* const* d_in, const int* in_sizes, int n_in,
                              void* d_out, int out_size, void* d_ws, size_t ws_size,
                              hipStream_t stream) {
    const float* z = (const float*)d_in[0];
    const float* E = (const float*)d_in[1];
    float* out = (float*)d_out;

    char* ws = (char*)d_ws;
    size_t off = 0;
    float*          En       = (float*)(ws + off);          off += (size_t)K_CODES * DDIM * 4;  // 8 MB
    unsigned short* En_b     = (unsigned short*)(ws + off); off += (size_t)K_CODES * DDIM * 2;  // 4 MB
    int*            cand_k   = (int*)(ws + off);            off += (size_t)M_ROWS * CAP * 4;    // 2 MB
    unsigned char*  cand_cnt = (unsigned char*)(ws + off);  off += (size_t)M_ROWS;              // 32 KB
    float*          rowloss  = (float*)(ws + off);

    k_norm_E<<<K_CODES / 4, 256, 0, stream>>>(E, En, En_b);
    k_cand<<<M_ROWS / BM, 256, 0, stream>>>(z, En_b, cand_cnt, cand_k);
    k_final<<<M_ROWS / 4, 256, 0, stream>>>(z, E, En, cand_cnt, cand_k, out, rowloss);
    k_loss<<<1, 256, 0, stream>>>(rowloss, out);
}